// Round 1
// baseline (386.975 us; speedup 1.0000x reference)
//
#include <hip/hip_runtime.h>

// ---------------------------------------------------------------------------
// NAT block forward: B=2, H=W=56, C=128, nh=4, hd=32, K=7, depth=2, hidden=512
// All fp32. Baseline: separate kernels per op, LDS staging for reuse.
// ---------------------------------------------------------------------------

__global__ __launch_bounds__(256) void copy_kernel(const float4* __restrict__ src,
                                                   float4* __restrict__ dst, int n4) {
  int i = blockIdx.x * blockDim.x + threadIdx.x;
  if (i < n4) dst[i] = src[i];
}

// LayerNorm over C=128. One wave per pixel, 4 pixels per 256-thread block.
__global__ __launch_bounds__(256) void ln_kernel(const float* __restrict__ in,
                                                 float* __restrict__ out,
                                                 const float* __restrict__ w,
                                                 const float* __restrict__ b,
                                                 int npix) {
  int wave = threadIdx.x >> 6;
  int lane = threadIdx.x & 63;
  int pix = blockIdx.x * 4 + wave;
  if (pix >= npix) return;
  const float* p = in + (size_t)pix * 128;
  float v0 = p[lane], v1 = p[lane + 64];
  float s = v0 + v1, s2 = v0 * v0 + v1 * v1;
#pragma unroll
  for (int off = 32; off; off >>= 1) {
    s += __shfl_xor(s, off, 64);
    s2 += __shfl_xor(s2, off, 64);
  }
  float mu = s * (1.f / 128.f);
  float var = s2 * (1.f / 128.f) - mu * mu;
  float r = rsqrtf(var + 1e-5f);
  float* q = out + (size_t)pix * 128;
  q[lane] = (v0 - mu) * r * w[lane] + b[lane];
  q[lane + 64] = (v1 - mu) * r * w[lane + 64] + b[lane + 64];
}

// GEMM: out[m][n] = act(sum_k in[m][k] * w[k][n] + bias[n]) (+ res[m][n])
// Block = N threads, MT pixels per block staged in LDS.
template <int K, int N, int MT, int ACT, int RES>
__global__ __launch_bounds__(512) void gemm_kernel(const float* __restrict__ in,
                                                   const float* __restrict__ w,
                                                   const float* __restrict__ bias,
                                                   const float* __restrict__ res,
                                                   float* __restrict__ out, int M) {
  __shared__ float s_in[MT][K];
  int m0 = blockIdx.x * MT;
  for (int idx = threadIdx.x; idx < MT * K; idx += N) {
    int mm = idx / K, kk = idx % K;
    s_in[mm][kk] = in[(size_t)(m0 + mm) * K + kk];
  }
  __syncthreads();
  int n = threadIdx.x;
  float bv = bias[n];
  float acc[MT];
#pragma unroll
  for (int mm = 0; mm < MT; ++mm) acc[mm] = bv;
  for (int k = 0; k < K; ++k) {
    float wv = w[(size_t)k * N + n];
#pragma unroll
    for (int mm = 0; mm < MT; ++mm) acc[mm] += s_in[mm][k] * wv;
  }
#pragma unroll
  for (int mm = 0; mm < MT; ++mm) {
    float a = acc[mm];
    if (ACT) a = 0.5f * a * (1.f + erff(a * 0.70710678118654752f));
    if (RES) a += res[(size_t)(m0 + mm) * N + n];
    out[(size_t)(m0 + mm) * N + n] = a;
  }
}

// Neighborhood attention, 7x7 clamped window.
// qkv layout per pixel: [3][nh=4][hd=32] -> q at h*32, k at 128+h*32, v at 256+h*32
// Block per pixel (6272), wave per head.
__global__ __launch_bounds__(256) void natten_kernel(const float* __restrict__ qkv,
                                                     const float* __restrict__ rpb,
                                                     float* __restrict__ out) {
  __shared__ float s_p[4][64];
  int pix = blockIdx.x;
  int j = pix % 56;
  int i = (pix / 56) % 56;
  int b = pix / 3136;
  int head = threadIdx.x >> 6;
  int lane = threadIdx.x & 63;

  int ri0 = min(max(i - 3, 0), 49);  // clip(i-3, 0, 56-7)
  int ci0 = min(max(j - 3, 0), 49);

  float score = -1e30f;
  if (lane < 49) {
    int wi = lane / 7, wj = lane % 7;
    int r = ri0 + wi, c = ci0 + wj;
    const float* qp = qkv + (size_t)pix * 384 + head * 32;
    const float* kp = qkv + (size_t)(b * 3136 + r * 56 + c) * 384 + 128 + head * 32;
    float acc = 0.f;
#pragma unroll 8
    for (int d = 0; d < 32; ++d) acc += qp[d] * kp[d];
    acc *= 0.17677669529663687f;  // 1/sqrt(32)
    int br = r - i + 6, bc = c - j + 6;
    acc += rpb[(head * 13 + br) * 13 + bc];
    score = acc;
  }
  // wave softmax over 49 entries
  float m = score;
#pragma unroll
  for (int off = 32; off; off >>= 1) m = fmaxf(m, __shfl_xor(m, off, 64));
  float e = (lane < 49) ? __expf(score - m) : 0.f;
  float ssum = e;
#pragma unroll
  for (int off = 32; off; off >>= 1) ssum += __shfl_xor(ssum, off, 64);
  s_p[head][lane] = e / ssum;
  __syncthreads();

  if (lane < 32) {
    float acc = 0.f;
    for (int nbr = 0; nbr < 49; ++nbr) {
      int wi = nbr / 7, wj = nbr % 7;
      int r = ri0 + wi, c = ci0 + wj;
      const float* vp = qkv + (size_t)(b * 3136 + r * 56 + c) * 384 + 256 + head * 32;
      acc += s_p[head][nbr] * vp[lane];
    }
    out[(size_t)pix * 128 + head * 32 + lane] = acc;
  }
}

// 3x3 stride-2 pad-1 conv (128->256) fused with LayerNorm over 256.
// 4 output pixels per block, thread per output channel.
__global__ __launch_bounds__(256) void conv_ln_kernel(const float* __restrict__ x,
                                                      const float* __restrict__ w,
                                                      const float* __restrict__ lnw,
                                                      const float* __restrict__ lnb,
                                                      float* __restrict__ out) {
  __shared__ float patch[4][1152];
  __shared__ float rs[4], rs2[4];
  int g = blockIdx.x;
  int oc = threadIdx.x;
  for (int t = 0; t < 4; ++t) {
    int opix = g * 4 + t;
    int ow = opix % 28, oh = (opix / 28) % 28, b = opix / 784;
    for (int idx = threadIdx.x; idx < 1152; idx += 256) {
      int ic = idx & 127, kk = idx >> 7;
      int kh = kk / 3, kw = kk % 3;
      int ih = 2 * oh - 1 + kh, iw = 2 * ow - 1 + kw;
      float v = 0.f;
      if (ih >= 0 && ih < 56 && iw >= 0 && iw < 56)
        v = x[(size_t)((b * 56 + ih) * 56 + iw) * 128 + ic];
      patch[t][idx] = v;
    }
  }
  __syncthreads();
  float acc[4] = {0.f, 0.f, 0.f, 0.f};
  for (int t = 0; t < 1152; ++t) {
    float wv = w[(size_t)t * 256 + oc];
#pragma unroll
    for (int p = 0; p < 4; ++p) acc[p] += patch[p][t] * wv;
  }
  for (int p = 0; p < 4; ++p) {
    float s = acc[p], s2 = acc[p] * acc[p];
#pragma unroll
    for (int off = 32; off; off >>= 1) {
      s += __shfl_xor(s, off, 64);
      s2 += __shfl_xor(s2, off, 64);
    }
    if ((threadIdx.x & 63) == 0) {
      rs[threadIdx.x >> 6] = s;
      rs2[threadIdx.x >> 6] = s2;
    }
    __syncthreads();
    s = rs[0] + rs[1] + rs[2] + rs[3];
    s2 = rs2[0] + rs2[1] + rs2[2] + rs2[3];
    __syncthreads();
    float mu = s * (1.f / 256.f);
    float var = s2 * (1.f / 256.f) - mu * mu;
    float r = rsqrtf(var + 1e-5f);
    out[(size_t)(g * 4 + p) * 256 + oc] = (acc[p] - mu) * r * lnw[oc] + lnb[oc];
  }
}

extern "C" void kernel_launch(void* const* d_in, const int* in_sizes, int n_in,
                              void* d_out, int out_size, void* d_ws, size_t ws_size,
                              hipStream_t stream) {
  const float* x    = (const float*)d_in[0];
  const float* n1w  = (const float*)d_in[1];
  const float* n1b  = (const float*)d_in[2];
  const float* qkvw = (const float*)d_in[3];
  const float* qkvb = (const float*)d_in[4];
  const float* rpb  = (const float*)d_in[5];
  const float* pw   = (const float*)d_in[6];
  const float* pb   = (const float*)d_in[7];
  const float* n2w  = (const float*)d_in[8];
  const float* n2b  = (const float*)d_in[9];
  const float* f1w  = (const float*)d_in[10];
  const float* f1b  = (const float*)d_in[11];
  const float* f2w  = (const float*)d_in[12];
  const float* f2b  = (const float*)d_in[13];
  const float* cw   = (const float*)d_in[14];
  const float* dnw  = (const float*)d_in[15];
  const float* dnb  = (const float*)d_in[16];
  float* out = (float*)d_out;

  float* ws   = (float*)d_ws;
  float* xbuf = ws;                // 802816 floats
  float* h    = ws + 802816;       // 802816
  float* qkv  = ws + 1605632;      // 2408448
  float* att  = ws + 4014080;      // 802816
  float* hid  = qkv;               // 3211264 (aliases qkv+att; both dead by fc1)
  // total: 4816896 floats = 19.3 MB

  copy_kernel<<<784, 256, 0, stream>>>((const float4*)x, (float4*)xbuf, 200704);

  for (int i = 0; i < 2; ++i) {
    ln_kernel<<<1568, 256, 0, stream>>>(xbuf, h, n1w + i * 128, n1b + i * 128, 6272);
    gemm_kernel<128, 384, 8, 0, 0><<<784, 384, 0, stream>>>(
        h, qkvw + i * 128 * 384, qkvb + i * 384, nullptr, qkv, 6272);
    natten_kernel<<<6272, 256, 0, stream>>>(qkv, rpb + i * 676, att);
    gemm_kernel<128, 128, 8, 0, 1><<<784, 128, 0, stream>>>(
        att, pw + i * 128 * 128, pb + i * 128, xbuf, xbuf, 6272);
    ln_kernel<<<1568, 256, 0, stream>>>(xbuf, h, n2w + i * 128, n2b + i * 128, 6272);
    gemm_kernel<128, 512, 8, 1, 0><<<784, 512, 0, stream>>>(
        h, f1w + i * 128 * 512, f1b + i * 512, nullptr, hid, 6272);
    gemm_kernel<512, 128, 8, 0, 1><<<784, 128, 0, stream>>>(
        hid, f2w + i * 512 * 128, f2b + i * 128, xbuf, xbuf, 6272);
  }

  conv_ln_kernel<<<392, 256, 0, stream>>>(xbuf, cw, dnw, dnb, out);
  copy_kernel<<<784, 256, 0, stream>>>((const float4*)xbuf, (float4*)(out + 401408), 200704);
}

// Round 2
// 364.790 us; speedup vs baseline: 1.0608x; 1.0608x over previous
//
#include <hip/hip_runtime.h>

// ---------------------------------------------------------------------------
// NAT block forward: B=2, H=W=56, C=128, nh=4, hd=32, K=7, depth=2, hidden=512
// fp32. Round 1: tiled natten w/ LDS halo staging, split-K conv, GEMM row-groups.
// ---------------------------------------------------------------------------

__global__ __launch_bounds__(256) void copy_kernel(const float4* __restrict__ src,
                                                   float4* __restrict__ dst, int n4) {
  int i = blockIdx.x * blockDim.x + threadIdx.x;
  if (i < n4) dst[i] = src[i];
}

// LayerNorm over C=128. One wave per pixel, 4 pixels per 256-thread block.
__global__ __launch_bounds__(256) void ln_kernel(const float* __restrict__ in,
                                                 float* __restrict__ out,
                                                 const float* __restrict__ w,
                                                 const float* __restrict__ b,
                                                 int npix) {
  int wave = threadIdx.x >> 6;
  int lane = threadIdx.x & 63;
  int pix = blockIdx.x * 4 + wave;
  if (pix >= npix) return;
  const float* p = in + (size_t)pix * 128;
  float v0 = p[lane], v1 = p[lane + 64];
  float s = v0 + v1, s2 = v0 * v0 + v1 * v1;
#pragma unroll
  for (int off = 32; off; off >>= 1) {
    s += __shfl_xor(s, off, 64);
    s2 += __shfl_xor(s2, off, 64);
  }
  float mu = s * (1.f / 128.f);
  float var = s2 * (1.f / 128.f) - mu * mu;
  float r = rsqrtf(var + 1e-5f);
  float* q = out + (size_t)pix * 128;
  q[lane] = (v0 - mu) * r * w[lane] + b[lane];
  q[lane + 64] = (v1 - mu) * r * w[lane + 64] + b[lane + 64];
}

// GEMM: out[m][n] = act(sum_k in[m][k] * w[k][n] + bias[n]) (+ res[m][n])
// Block = N*RG threads; RG row-groups each own MT rows (MT*RG rows per block).
template <int K, int N, int MT, int RG, int ACT, int RES>
__global__ __launch_bounds__(512) void gemm_kernel(const float* __restrict__ in,
                                                   const float* __restrict__ w,
                                                   const float* __restrict__ bias,
                                                   const float* __restrict__ res,
                                                   float* __restrict__ out, int M) {
  __shared__ float s_in[MT * RG][K];
  int m0 = blockIdx.x * (MT * RG);
  for (int idx = threadIdx.x; idx < MT * RG * K; idx += N * RG) {
    int mm = idx / K, kk = idx % K;
    s_in[mm][kk] = in[(size_t)(m0 + mm) * K + kk];
  }
  __syncthreads();
  int n = threadIdx.x % N;
  int mbase = (threadIdx.x / N) * MT;
  float bv = bias[n];
  float acc[MT];
#pragma unroll
  for (int mm = 0; mm < MT; ++mm) acc[mm] = bv;
#pragma unroll 4
  for (int k = 0; k < K; ++k) {
    float wv = w[(size_t)k * N + n];
#pragma unroll
    for (int mm = 0; mm < MT; ++mm) acc[mm] += s_in[mbase + mm][k] * wv;
  }
#pragma unroll
  for (int mm = 0; mm < MT; ++mm) {
    float a = acc[mm];
    if (ACT) a = 0.5f * a * (1.f + erff(a * 0.70710678118654752f));
    if (RES) a += res[(size_t)(m0 + mbase + mm) * N + n];
    out[(size_t)(m0 + mbase + mm) * N + n] = a;
  }
}

// Neighborhood attention, 7x7 clamped window, tiled.
// Block = one (batch, head, 8x8 pixel tile). Grid = 49 tiles * 8 (b*4+head).
// K/V 14x14 halo + scaled Q + rpb staged in LDS.
__global__ __launch_bounds__(256) void natten_tiled(const float* __restrict__ qkv,
                                                    const float* __restrict__ rpb,
                                                    float* __restrict__ out) {
  __shared__ float s_k[196][33];
  __shared__ float s_v[196][33];
  __shared__ float s_q[64][32];
  __shared__ float s_rpb[169];
  __shared__ float s_p[4][64];

  int blk = blockIdx.x;
  int bh = blk & 7;
  int tile = blk >> 3;
  int b = bh >> 2, head = bh & 3;
  int ti = tile / 7, tj = tile % 7;
  int i0 = ti * 8, j0 = tj * 8;
  int rbase = min(max(i0 - 3, 0), 42);
  int cbase = min(max(j0 - 3, 0), 42);
  int tid = threadIdx.x;

  // stage K, V halo (14x14 x 32d)
  for (int idx = tid; idx < 196 * 32; idx += 256) {
    int pos = idx >> 5, d = idx & 31;
    int r = rbase + pos / 14, c = cbase + pos % 14;
    size_t base = ((size_t)(b * 3136 + r * 56 + c)) * 384 + head * 32 + d;
    s_k[pos][d] = qkv[base + 128];
    s_v[pos][d] = qkv[base + 256];
  }
  // stage Q (pre-scaled)
  for (int idx = tid; idx < 64 * 32; idx += 256) {
    int p = idx >> 5, d = idx & 31;
    int i = i0 + (p >> 3), j = j0 + (p & 7);
    s_q[p][d] =
        qkv[((size_t)(b * 3136 + i * 56 + j)) * 384 + head * 32 + d] * 0.17677669529663687f;
  }
  for (int idx = tid; idx < 169; idx += 256) s_rpb[idx] = rpb[head * 169 + idx];
  __syncthreads();

  int wave = tid >> 6, lane = tid & 63;
  int wi = lane / 7, wj = lane - wi * 7;  // valid for lane < 49
  for (int pp = 0; pp < 16; ++pp) {
    int p = wave * 16 + pp;
    int i = i0 + (p >> 3), j = j0 + (p & 7);
    int rs = min(max(i - 3, 0), 49);
    int cs = min(max(j - 3, 0), 49);
    int wpos0 = (rs - rbase) * 14 + (cs - cbase);
    float score = -1e30f;
    if (lane < 49) {
      int pos = wpos0 + wi * 14 + wj;
      float acc = 0.f;
#pragma unroll
      for (int d = 0; d < 32; ++d) acc += s_q[p][d] * s_k[pos][d];
      score = acc + s_rpb[(rs + wi - i + 6) * 13 + (cs + wj - j + 6)];
    }
    float m = score;
#pragma unroll
    for (int off = 32; off; off >>= 1) m = fmaxf(m, __shfl_xor(m, off, 64));
    float e = (lane < 49) ? __expf(score - m) : 0.f;
    float ss = e;
#pragma unroll
    for (int off = 32; off; off >>= 1) ss += __shfl_xor(ss, off, 64);
    s_p[wave][lane] = e / ss;  // wave-local buffer: no barrier needed

    int g = lane >> 5, d = lane & 31;
    float acc = 0.f;
    for (int n = g; n < 49; n += 2) {
      int nwi = n / 7, nwj = n - nwi * 7;
      acc += s_p[wave][n] * s_v[wpos0 + nwi * 14 + nwj][d];
    }
    acc += __shfl_xor(acc, 32, 64);
    if (lane < 32)
      out[((size_t)(b * 3136 + i * 56 + j)) * 128 + head * 32 + d] = acc;
  }
}

// 3x3 stride-2 pad-1 conv (128->256) fused with LayerNorm over 256.
// 4 output pixels per block, 512 threads: thread = (oc, K-half). 392 blocks.
__global__ __launch_bounds__(512) void conv_ln_kernel(const float* __restrict__ x,
                                                      const float* __restrict__ w,
                                                      const float* __restrict__ lnw,
                                                      const float* __restrict__ lnb,
                                                      float* __restrict__ out) {
  __shared__ float patch[4][1152];
  __shared__ float s_red[4][256];
  __shared__ float cw_s[8], cw_s2[8];
  int g = blockIdx.x;
  int tid = threadIdx.x;
  int oc = tid & 255, half = tid >> 8;

  for (int t = 0; t < 4; ++t) {
    int opix = g * 4 + t;
    int ow = opix % 28, oh = (opix / 28) % 28, b = opix / 784;
    for (int idx = tid; idx < 1152; idx += 512) {
      int ic = idx & 127, kk = idx >> 7;
      int kh = kk / 3, kw = kk % 3;
      int ih = 2 * oh - 1 + kh, iw = 2 * ow - 1 + kw;
      float v = 0.f;
      if (ih >= 0 && ih < 56 && iw >= 0 && iw < 56)
        v = x[(size_t)((b * 56 + ih) * 56 + iw) * 128 + ic];
      patch[t][idx] = v;
    }
  }
  __syncthreads();

  float acc[4] = {0.f, 0.f, 0.f, 0.f};
  const float* wp = w + (size_t)half * 576 * 256 + oc;
#pragma unroll 4
  for (int t = 0; t < 576; ++t) {
    float wv = wp[(size_t)t * 256];
    int tt = half * 576 + t;
#pragma unroll
    for (int p = 0; p < 4; ++p) acc[p] += patch[p][tt] * wv;
  }
  if (half == 1) {
#pragma unroll
    for (int p = 0; p < 4; ++p) s_red[p][oc] = acc[p];
  }
  __syncthreads();
  if (half == 0) {
#pragma unroll
    for (int p = 0; p < 4; ++p) s_red[p][oc] = acc[p] + s_red[p][oc];
  }
  __syncthreads();

  // LN: thread -> (pixel p = tid>>7, channels c, c+128). Waves 2p, 2p+1 serve pixel p.
  int p = tid >> 7, c = tid & 127;
  int wave = tid >> 6, lane = tid & 63;
  float v0 = s_red[p][c], v1 = s_red[p][c + 128];
  float s = v0 + v1, s2 = v0 * v0 + v1 * v1;
#pragma unroll
  for (int off = 32; off; off >>= 1) {
    s += __shfl_xor(s, off, 64);
    s2 += __shfl_xor(s2, off, 64);
  }
  if (lane == 0) {
    cw_s[wave] = s;
    cw_s2[wave] = s2;
  }
  __syncthreads();
  s = cw_s[p * 2] + cw_s[p * 2 + 1];
  s2 = cw_s2[p * 2] + cw_s2[p * 2 + 1];
  float mu = s * (1.f / 256.f);
  float var = s2 * (1.f / 256.f) - mu * mu;
  float r = rsqrtf(var + 1e-5f);
  size_t ob = (size_t)(g * 4 + p) * 256;
  out[ob + c] = (v0 - mu) * r * lnw[c] + lnb[c];
  out[ob + c + 128] = (v1 - mu) * r * lnw[c + 128] + lnb[c + 128];
}

extern "C" void kernel_launch(void* const* d_in, const int* in_sizes, int n_in,
                              void* d_out, int out_size, void* d_ws, size_t ws_size,
                              hipStream_t stream) {
  const float* x    = (const float*)d_in[0];
  const float* n1w  = (const float*)d_in[1];
  const float* n1b  = (const float*)d_in[2];
  const float* qkvw = (const float*)d_in[3];
  const float* qkvb = (const float*)d_in[4];
  const float* rpb  = (const float*)d_in[5];
  const float* pw   = (const float*)d_in[6];
  const float* pb   = (const float*)d_in[7];
  const float* n2w  = (const float*)d_in[8];
  const float* n2b  = (const float*)d_in[9];
  const float* f1w  = (const float*)d_in[10];
  const float* f1b  = (const float*)d_in[11];
  const float* f2w  = (const float*)d_in[12];
  const float* f2b  = (const float*)d_in[13];
  const float* cw   = (const float*)d_in[14];
  const float* dnw  = (const float*)d_in[15];
  const float* dnb  = (const float*)d_in[16];
  float* out = (float*)d_out;

  float* ws   = (float*)d_ws;
  float* xbuf = ws;                // 802816 floats
  float* h    = ws + 802816;       // 802816
  float* qkv  = ws + 1605632;      // 2408448
  float* att  = ws + 4014080;      // 802816
  float* hid  = qkv;               // 3211264 (aliases qkv+att; both dead by fc1)

  copy_kernel<<<784, 256, 0, stream>>>((const float4*)x, (float4*)xbuf, 200704);

  for (int i = 0; i < 2; ++i) {
    ln_kernel<<<1568, 256, 0, stream>>>(xbuf, h, n1w + i * 128, n1b + i * 128, 6272);
    gemm_kernel<128, 384, 8, 1, 0, 0><<<784, 384, 0, stream>>>(
        h, qkvw + i * 128 * 384, qkvb + i * 384, nullptr, qkv, 6272);
    natten_tiled<<<392, 256, 0, stream>>>(qkv, rpb + i * 676, att);
    gemm_kernel<128, 128, 4, 4, 0, 1><<<392, 512, 0, stream>>>(
        att, pw + i * 128 * 128, pb + i * 128, xbuf, xbuf, 6272);
    ln_kernel<<<1568, 256, 0, stream>>>(xbuf, h, n2w + i * 128, n2b + i * 128, 6272);
    gemm_kernel<128, 512, 8, 1, 1, 0><<<784, 512, 0, stream>>>(
        h, f1w + i * 128 * 512, f1b + i * 512, nullptr, hid, 6272);
    gemm_kernel<512, 128, 4, 4, 0, 1><<<392, 512, 0, stream>>>(
        hid, f2w + i * 512 * 128, f2b + i * 128, xbuf, xbuf, 6272);
  }

  conv_ln_kernel<<<392, 512, 0, stream>>>(xbuf, cw, dnw, dnb, out);
  copy_kernel<<<784, 256, 0, stream>>>((const float4*)xbuf, (float4*)(out + 401408), 200704);
}

// Round 3
// 238.694 us; speedup vs baseline: 1.6212x; 1.5283x over previous
//
#include <hip/hip_runtime.h>
#include <stdint.h>

// ---------------------------------------------------------------------------
// NAT block forward: B=2, H=W=56, C=128, nh=4, hd=32, K=7, depth=2, hidden=512
// Round 3: all GEMM-shaped ops -> bf16 MFMA (16x16x32), fp32 accum.
// ---------------------------------------------------------------------------

typedef __attribute__((ext_vector_type(8))) short bf16x8;
typedef __attribute__((ext_vector_type(4))) float f32x4;

__device__ __forceinline__ float bf2f(uint16_t u) {
  union { uint32_t u; float f; } t;
  t.u = (uint32_t)u << 16;
  return t.f;
}
__device__ __forceinline__ uint16_t f2bf(float f) {
  union { float f; uint32_t u; } t;
  t.f = f;
  return (uint16_t)((t.u + 0x7FFFu + ((t.u >> 16) & 1u)) >> 16);
}

__global__ __launch_bounds__(256) void copy_kernel(const float4* __restrict__ src,
                                                   float4* __restrict__ dst, int n4) {
  int i = blockIdx.x * blockDim.x + threadIdx.x;
  if (i < n4) dst[i] = src[i];
}

// Tiled transpose + bf16 convert: w[K][N] f32 -> wt[N][K] bf16.
// grid (N/32, K/32), block 256.
__global__ __launch_bounds__(256) void transpose_w(const float* __restrict__ w,
                                                   uint16_t* __restrict__ wt,
                                                   int K, int N) {
  __shared__ float t[32][33];
  int n0 = blockIdx.x * 32, k0 = blockIdx.y * 32;
  int tx = threadIdx.x & 31, ty = threadIdx.x >> 5;
#pragma unroll
  for (int r = 0; r < 32; r += 8) t[ty + r][tx] = w[(size_t)(k0 + ty + r) * N + n0 + tx];
  __syncthreads();
#pragma unroll
  for (int r = 0; r < 32; r += 8)
    wt[(size_t)(n0 + ty + r) * K + k0 + tx] = f2bf(t[tx][ty + r]);
}

// LayerNorm over C=128, fp32 in -> bf16 out. Wave per pixel, 4 pixels/block.
__global__ __launch_bounds__(256) void ln_kernel(const float* __restrict__ in,
                                                 uint16_t* __restrict__ out,
                                                 const float* __restrict__ w,
                                                 const float* __restrict__ b) {
  int wave = threadIdx.x >> 6, lane = threadIdx.x & 63;
  int pix = blockIdx.x * 4 + wave;
  const float* p = in + (size_t)pix * 128;
  float v0 = p[lane], v1 = p[lane + 64];
  float s = v0 + v1, s2 = v0 * v0 + v1 * v1;
#pragma unroll
  for (int off = 32; off; off >>= 1) {
    s += __shfl_xor(s, off, 64);
    s2 += __shfl_xor(s2, off, 64);
  }
  float mu = s * (1.f / 128.f);
  float var = s2 * (1.f / 128.f) - mu * mu;
  float r = rsqrtf(var + 1e-5f);
  uint16_t* q = out + (size_t)pix * 128;
  q[lane] = f2bf((v0 - mu) * r * w[lane] + b[lane]);
  q[lane + 64] = f2bf((v1 - mu) * r * w[lane + 64] + b[lane + 64]);
}

// LayerNorm over C=256, fp32 in -> fp32 out (d_out). Wave per pixel.
__global__ __launch_bounds__(256) void ln256_kernel(const float* __restrict__ in,
                                                    float* __restrict__ out,
                                                    const float* __restrict__ w,
                                                    const float* __restrict__ b) {
  int wave = threadIdx.x >> 6, lane = threadIdx.x & 63;
  int pix = blockIdx.x * 4 + wave;
  const float* p = in + (size_t)pix * 256;
  float v0 = p[lane], v1 = p[lane + 64], v2 = p[lane + 128], v3 = p[lane + 192];
  float s = v0 + v1 + v2 + v3;
  float s2 = v0 * v0 + v1 * v1 + v2 * v2 + v3 * v3;
#pragma unroll
  for (int off = 32; off; off >>= 1) {
    s += __shfl_xor(s, off, 64);
    s2 += __shfl_xor(s2, off, 64);
  }
  float mu = s * (1.f / 256.f);
  float var = s2 * (1.f / 256.f) - mu * mu;
  float r = rsqrtf(var + 1e-5f);
  float* q = out + (size_t)pix * 256;
  q[lane] = (v0 - mu) * r * w[lane] + b[lane];
  q[lane + 64] = (v1 - mu) * r * w[lane + 64] + b[lane + 64];
  q[lane + 128] = (v2 - mu) * r * w[lane + 128] + b[lane + 128];
  q[lane + 192] = (v3 - mu) * r * w[lane + 192] + b[lane + 192];
}

// MFMA GEMM: out[m][n] = epi(sum_k A[m][k]*Wt[n][k] + bias[n]).
// A bf16 [M][KD], Wt bf16 [ND][KD]. 64x64 tile, 4 waves (2x2), wave = 32x32.
template <int KD, int ND, int ACT, int RES, int OUTB>
__global__ __launch_bounds__(256) void mfma_gemm(const uint16_t* __restrict__ A,
                                                 const uint16_t* __restrict__ Wt,
                                                 const float* __restrict__ bias,
                                                 const float* __restrict__ res,
                                                 float* __restrict__ outf,
                                                 uint16_t* __restrict__ outb, int M) {
  __shared__ uint16_t sA[64][72];
  __shared__ uint16_t sB[64][72];
  int m0 = blockIdx.x * 64, n0 = blockIdx.y * 64;
  int tid = threadIdx.x, lane = tid & 63, wid = tid >> 6;
  int wr = (wid >> 1) * 32, wc = (wid & 1) * 32;
  int lrow = lane & 15, lko = (lane >> 4) * 8;

  f32x4 acc00 = {0.f, 0.f, 0.f, 0.f}, acc01 = acc00, acc10 = acc00, acc11 = acc00;

  for (int k0 = 0; k0 < KD; k0 += 64) {
#pragma unroll
    for (int it = 0; it < 2; ++it) {
      int chunk = tid + it * 256;
      int row = chunk >> 3, kc = (chunk & 7) * 8;
      *(bf16x8*)&sA[row][kc] = *(const bf16x8*)(A + (size_t)(m0 + row) * KD + k0 + kc);
      *(bf16x8*)&sB[row][kc] = *(const bf16x8*)(Wt + (size_t)(n0 + row) * KD + k0 + kc);
    }
    __syncthreads();
#pragma unroll
    for (int kk = 0; kk < 64; kk += 32) {
      bf16x8 a0 = *(const bf16x8*)&sA[wr + lrow][kk + lko];
      bf16x8 a1 = *(const bf16x8*)&sA[wr + 16 + lrow][kk + lko];
      bf16x8 b0 = *(const bf16x8*)&sB[wc + lrow][kk + lko];
      bf16x8 b1 = *(const bf16x8*)&sB[wc + 16 + lrow][kk + lko];
      acc00 = __builtin_amdgcn_mfma_f32_16x16x32_bf16(a0, b0, acc00, 0, 0, 0);
      acc01 = __builtin_amdgcn_mfma_f32_16x16x32_bf16(a0, b1, acc01, 0, 0, 0);
      acc10 = __builtin_amdgcn_mfma_f32_16x16x32_bf16(a1, b0, acc10, 0, 0, 0);
      acc11 = __builtin_amdgcn_mfma_f32_16x16x32_bf16(a1, b1, acc11, 0, 0, 0);
    }
    __syncthreads();
  }

  // C/D layout: col = lane&15, row = (lane>>4)*4 + j
  int rbase = m0 + wr + (lane >> 4) * 4;
  int cb0 = n0 + wc + lrow, cb1 = cb0 + 16;
  float bv0 = bias ? bias[cb0] : 0.f;
  float bv1 = bias ? bias[cb1] : 0.f;
  f32x4 av[2][2] = {{acc00, acc01}, {acc10, acc11}};
#pragma unroll
  for (int mi = 0; mi < 2; ++mi) {
#pragma unroll
    for (int ni = 0; ni < 2; ++ni) {
      int col = ni ? cb1 : cb0;
      float bv = ni ? bv1 : bv0;
#pragma unroll
      for (int j = 0; j < 4; ++j) {
        int row = rbase + mi * 16 + j;
        if (row < M) {
          float a = av[mi][ni][j] + bv;
          if (ACT) a = 0.5f * a * (1.f + erff(a * 0.70710678118654752f));
          if (RES) a += res[(size_t)row * ND + col];
          if (OUTB) outb[(size_t)row * ND + col] = f2bf(a);
          else outf[(size_t)row * ND + col] = a;
        }
      }
    }
  }
}

// Neighborhood attention, 7x7 clamped window, tiled. bf16 in/out, fp32 math.
// Block = (batch, head, 8x8 pixel tile). Grid = 49*8.
__global__ __launch_bounds__(256) void natten_tiled(const uint16_t* __restrict__ qkv,
                                                    const float* __restrict__ rpb,
                                                    uint16_t* __restrict__ out) {
  __shared__ float s_k[196][33];
  __shared__ float s_v[196][33];
  __shared__ float s_q[64][32];
  __shared__ float s_rpb[169];
  __shared__ float s_p[4][64];

  int blk = blockIdx.x;
  int bh = blk & 7;
  int tile = blk >> 3;
  int b = bh >> 2, head = bh & 3;
  int ti = tile / 7, tj = tile % 7;
  int i0 = ti * 8, j0 = tj * 8;
  int rbase = min(max(i0 - 3, 0), 42);
  int cbase = min(max(j0 - 3, 0), 42);
  int tid = threadIdx.x;

  for (int idx = tid; idx < 196 * 8; idx += 256) {
    int pos = idx >> 3, dc = (idx & 7) * 4;
    int r = rbase + pos / 14, c = cbase + pos % 14;
    const uint16_t* base = qkv + ((size_t)(b * 3136 + r * 56 + c)) * 384 + head * 32 + dc;
    ushort4 kv = *(const ushort4*)(base + 128);
    ushort4 vv = *(const ushort4*)(base + 256);
    s_k[pos][dc] = bf2f(kv.x);
    s_k[pos][dc + 1] = bf2f(kv.y);
    s_k[pos][dc + 2] = bf2f(kv.z);
    s_k[pos][dc + 3] = bf2f(kv.w);
    s_v[pos][dc] = bf2f(vv.x);
    s_v[pos][dc + 1] = bf2f(vv.y);
    s_v[pos][dc + 2] = bf2f(vv.z);
    s_v[pos][dc + 3] = bf2f(vv.w);
  }
  for (int idx = tid; idx < 64 * 8; idx += 256) {
    int p = idx >> 3, dc = (idx & 7) * 4;
    int i = i0 + (p >> 3), j = j0 + (p & 7);
    ushort4 qv = *(const ushort4*)(qkv + ((size_t)(b * 3136 + i * 56 + j)) * 384 + head * 32 + dc);
    s_q[p][dc] = bf2f(qv.x) * 0.17677669529663687f;
    s_q[p][dc + 1] = bf2f(qv.y) * 0.17677669529663687f;
    s_q[p][dc + 2] = bf2f(qv.z) * 0.17677669529663687f;
    s_q[p][dc + 3] = bf2f(qv.w) * 0.17677669529663687f;
  }
  for (int idx = tid; idx < 169; idx += 256) s_rpb[idx] = rpb[head * 169 + idx];
  __syncthreads();

  int wave = tid >> 6, lane = tid & 63;
  int wi = lane / 7, wj = lane - wi * 7;
  for (int pp = 0; pp < 16; ++pp) {
    int p = wave * 16 + pp;
    int i = i0 + (p >> 3), j = j0 + (p & 7);
    int rs = min(max(i - 3, 0), 49);
    int cs = min(max(j - 3, 0), 49);
    int wpos0 = (rs - rbase) * 14 + (cs - cbase);
    float score = -1e30f;
    if (lane < 49) {
      int pos = wpos0 + wi * 14 + wj;
      float acc = 0.f;
#pragma unroll
      for (int d = 0; d < 32; ++d) acc += s_q[p][d] * s_k[pos][d];
      score = acc + s_rpb[(rs + wi - i + 6) * 13 + (cs + wj - j + 6)];
    }
    float m = score;
#pragma unroll
    for (int off = 32; off; off >>= 1) m = fmaxf(m, __shfl_xor(m, off, 64));
    float e = (lane < 49) ? __expf(score - m) : 0.f;
    float ss = e;
#pragma unroll
    for (int off = 32; off; off >>= 1) ss += __shfl_xor(ss, off, 64);
    s_p[wave][lane] = e / ss;

    int g = lane >> 5, d = lane & 31;
    float acc = 0.f;
    for (int n = g; n < 49; n += 2) {
      int nwi = n / 7, nwj = n - nwi * 7;
      acc += s_p[wave][n] * s_v[wpos0 + nwi * 14 + nwj][d];
    }
    acc += __shfl_xor(acc, 32, 64);
    if (lane < 32)
      out[((size_t)(b * 3136 + i * 56 + j)) * 128 + head * 32 + d] = f2bf(acc);
  }
}

// im2col for 3x3 stride-2 pad-1 conv: xbuf f32 [2][56][56][128] -> col bf16 [1600][1152]
// rows >= 1568 zero-filled. Each thread writes one 8-channel chunk.
__global__ __launch_bounds__(256) void im2col_kernel(const float* __restrict__ x,
                                                     uint16_t* __restrict__ col) {
  int chunk = blockIdx.x * 256 + threadIdx.x;  // 230400 total
  int row = chunk / 144, cc = chunk - row * 144;
  int t = cc * 8, kk = t >> 7, ic = t & 127;
  float v[8] = {0.f, 0.f, 0.f, 0.f, 0.f, 0.f, 0.f, 0.f};
  if (row < 1568) {
    int ow = row % 28, oh = (row / 28) % 28, bb = row / 784;
    int ih = 2 * oh - 1 + kk / 3, iw = 2 * ow - 1 + kk % 3;
    if (ih >= 0 && ih < 56 && iw >= 0 && iw < 56) {
      const float4* p = (const float4*)(x + (size_t)((bb * 56 + ih) * 56 + iw) * 128 + ic);
      float4 p0 = p[0], p1 = p[1];
      v[0] = p0.x; v[1] = p0.y; v[2] = p0.z; v[3] = p0.w;
      v[4] = p1.x; v[5] = p1.y; v[6] = p1.z; v[7] = p1.w;
    }
  }
  union { uint16_t us[8]; bf16x8 vv; } tmp;
#pragma unroll
  for (int i2 = 0; i2 < 8; ++i2) tmp.us[i2] = f2bf(v[i2]);
  *(bf16x8*)(col + (size_t)row * 1152 + t) = tmp.vv;
}

extern "C" void kernel_launch(void* const* d_in, const int* in_sizes, int n_in,
                              void* d_out, int out_size, void* d_ws, size_t ws_size,
                              hipStream_t stream) {
  const float* x    = (const float*)d_in[0];
  const float* n1w  = (const float*)d_in[1];
  const float* n1b  = (const float*)d_in[2];
  const float* qkvw = (const float*)d_in[3];
  const float* qkvb = (const float*)d_in[4];
  const float* rpb  = (const float*)d_in[5];
  const float* pw   = (const float*)d_in[6];
  const float* pb   = (const float*)d_in[7];
  const float* n2w  = (const float*)d_in[8];
  const float* n2b  = (const float*)d_in[9];
  const float* f1w  = (const float*)d_in[10];
  const float* f1b  = (const float*)d_in[11];
  const float* f2w  = (const float*)d_in[12];
  const float* f2b  = (const float*)d_in[13];
  const float* cw   = (const float*)d_in[14];
  const float* dnw  = (const float*)d_in[15];
  const float* dnb  = (const float*)d_in[16];
  float* out = (float*)d_out;

  // workspace layout (bytes):
  char* wsb = (char*)d_ws;
  float* xbuf      = (float*)(wsb + 0);          // 3211264 B
  uint16_t* h_b    = (uint16_t*)(wsb + 3211264);  // 1605632 B
  uint16_t* qkv_b  = (uint16_t*)(wsb + 4816896);  // 4816896 B (aliased by col)
  uint16_t* att_b  = (uint16_t*)(wsb + 9633792);  // 1605632 B (aliased by convout)
  uint16_t* hid_b  = (uint16_t*)(wsb + 11239424); // 6422528 B
  uint16_t* wts    = (uint16_t*)(wsb + 17661952); // 1376256 B  -> total 19038208 B
  uint16_t* col_b   = qkv_b;
  float*    convout = (float*)att_b;
  uint16_t* qkvwt = wts;            // 2 x 384x128
  uint16_t* pwt   = wts + 98304;    // 2 x 128x128
  uint16_t* f1wt  = wts + 131072;   // 2 x 512x128
  uint16_t* f2wt  = wts + 262144;   // 2 x 128x512
  uint16_t* cwt   = wts + 393216;   // 256x1152

  // weight prep (transpose + bf16)
  transpose_w<<<dim3(12, 4), 256, 0, stream>>>(qkvw, qkvwt, 128, 384);
  transpose_w<<<dim3(12, 4), 256, 0, stream>>>(qkvw + 49152, qkvwt + 49152, 128, 384);
  transpose_w<<<dim3(4, 4), 256, 0, stream>>>(pw, pwt, 128, 128);
  transpose_w<<<dim3(4, 4), 256, 0, stream>>>(pw + 16384, pwt + 16384, 128, 128);
  transpose_w<<<dim3(16, 4), 256, 0, stream>>>(f1w, f1wt, 128, 512);
  transpose_w<<<dim3(16, 4), 256, 0, stream>>>(f1w + 65536, f1wt + 65536, 128, 512);
  transpose_w<<<dim3(4, 16), 256, 0, stream>>>(f2w, f2wt, 512, 128);
  transpose_w<<<dim3(4, 16), 256, 0, stream>>>(f2w + 65536, f2wt + 65536, 512, 128);
  transpose_w<<<dim3(8, 36), 256, 0, stream>>>(cw, cwt, 1152, 256);

  for (int i = 0; i < 2; ++i) {
    const float* xin = (i == 0) ? x : xbuf;
    ln_kernel<<<1568, 256, 0, stream>>>(xin, h_b, n1w + i * 128, n1b + i * 128);
    mfma_gemm<128, 384, 0, 0, 1><<<dim3(98, 6), 256, 0, stream>>>(
        h_b, qkvwt + i * 49152, qkvb + i * 384, nullptr, nullptr, qkv_b, 6272);
    natten_tiled<<<392, 256, 0, stream>>>(qkv_b, rpb + i * 676, att_b);
    mfma_gemm<128, 128, 0, 1, 0><<<dim3(98, 2), 256, 0, stream>>>(
        att_b, pwt + i * 16384, pb + i * 128, xin, xbuf, nullptr, 6272);
    ln_kernel<<<1568, 256, 0, stream>>>(xbuf, h_b, n2w + i * 128, n2b + i * 128);
    mfma_gemm<128, 512, 1, 0, 1><<<dim3(98, 8), 256, 0, stream>>>(
        h_b, f1wt + i * 65536, f1b + i * 512, nullptr, nullptr, hid_b, 6272);
    mfma_gemm<512, 128, 0, 1, 0><<<dim3(98, 2), 256, 0, stream>>>(
        hid_b, f2wt + i * 65536, f2b + i * 128, xbuf, xbuf, nullptr, 6272);
  }

  im2col_kernel<<<900, 256, 0, stream>>>(xbuf, col_b);
  mfma_gemm<1152, 256, 0, 0, 0><<<dim3(25, 4), 256, 0, stream>>>(
      col_b, cwt, nullptr, nullptr, convout, nullptr, 1568);
  ln256_kernel<<<392, 256, 0, stream>>>(convout, out, dnw, dnb);
  copy_kernel<<<784, 256, 0, stream>>>((const float4*)xbuf, (float4*)(out + 401408), 200704);
}

// Round 4
// 169.658 us; speedup vs baseline: 2.2809x; 1.4069x over previous
//
#include <hip/hip_runtime.h>
#include <stdint.h>

// ---------------------------------------------------------------------------
// NAT block forward: B=2, H=W=56, C=128, nh=4, hd=32, K=7, depth=2, hidden=512
// Round 4: natten -> MFMA (dense 64x224 masked attention per 8x8 tile).
// ---------------------------------------------------------------------------

typedef __attribute__((ext_vector_type(8))) short bf16x8;
typedef __attribute__((ext_vector_type(4))) float f32x4;

__device__ __forceinline__ float bf2f(uint16_t u) {
  union { uint32_t u; float f; } t;
  t.u = (uint32_t)u << 16;
  return t.f;
}
__device__ __forceinline__ uint16_t f2bf(float f) {
  union { float f; uint32_t u; } t;
  t.f = f;
  return (uint16_t)((t.u + 0x7FFFu + ((t.u >> 16) & 1u)) >> 16);
}

__global__ __launch_bounds__(256) void copy_kernel(const float4* __restrict__ src,
                                                   float4* __restrict__ dst, int n4) {
  int i = blockIdx.x * blockDim.x + threadIdx.x;
  if (i < n4) dst[i] = src[i];
}

// Tiled transpose + bf16 convert: w[K][N] f32 -> wt[N][K] bf16.
__global__ __launch_bounds__(256) void transpose_w(const float* __restrict__ w,
                                                   uint16_t* __restrict__ wt,
                                                   int K, int N) {
  __shared__ float t[32][33];
  int n0 = blockIdx.x * 32, k0 = blockIdx.y * 32;
  int tx = threadIdx.x & 31, ty = threadIdx.x >> 5;
#pragma unroll
  for (int r = 0; r < 32; r += 8) t[ty + r][tx] = w[(size_t)(k0 + ty + r) * N + n0 + tx];
  __syncthreads();
#pragma unroll
  for (int r = 0; r < 32; r += 8)
    wt[(size_t)(n0 + ty + r) * K + k0 + tx] = f2bf(t[tx][ty + r]);
}

// LayerNorm over C=128, fp32 in -> bf16 out. Wave per pixel, 4 pixels/block.
__global__ __launch_bounds__(256) void ln_kernel(const float* __restrict__ in,
                                                 uint16_t* __restrict__ out,
                                                 const float* __restrict__ w,
                                                 const float* __restrict__ b) {
  int wave = threadIdx.x >> 6, lane = threadIdx.x & 63;
  int pix = blockIdx.x * 4 + wave;
  const float* p = in + (size_t)pix * 128;
  float v0 = p[lane], v1 = p[lane + 64];
  float s = v0 + v1, s2 = v0 * v0 + v1 * v1;
#pragma unroll
  for (int off = 32; off; off >>= 1) {
    s += __shfl_xor(s, off, 64);
    s2 += __shfl_xor(s2, off, 64);
  }
  float mu = s * (1.f / 128.f);
  float var = s2 * (1.f / 128.f) - mu * mu;
  float r = rsqrtf(var + 1e-5f);
  uint16_t* q = out + (size_t)pix * 128;
  q[lane] = f2bf((v0 - mu) * r * w[lane] + b[lane]);
  q[lane + 64] = f2bf((v1 - mu) * r * w[lane + 64] + b[lane + 64]);
}

// LayerNorm over C=256, fp32 in -> fp32 out (d_out). Wave per pixel.
__global__ __launch_bounds__(256) void ln256_kernel(const float* __restrict__ in,
                                                    float* __restrict__ out,
                                                    const float* __restrict__ w,
                                                    const float* __restrict__ b) {
  int wave = threadIdx.x >> 6, lane = threadIdx.x & 63;
  int pix = blockIdx.x * 4 + wave;
  const float* p = in + (size_t)pix * 256;
  float v0 = p[lane], v1 = p[lane + 64], v2 = p[lane + 128], v3 = p[lane + 192];
  float s = v0 + v1 + v2 + v3;
  float s2 = v0 * v0 + v1 * v1 + v2 * v2 + v3 * v3;
#pragma unroll
  for (int off = 32; off; off >>= 1) {
    s += __shfl_xor(s, off, 64);
    s2 += __shfl_xor(s2, off, 64);
  }
  float mu = s * (1.f / 256.f);
  float var = s2 * (1.f / 256.f) - mu * mu;
  float r = rsqrtf(var + 1e-5f);
  float* q = out + (size_t)pix * 256;
  q[lane] = (v0 - mu) * r * w[lane] + b[lane];
  q[lane + 64] = (v1 - mu) * r * w[lane + 64] + b[lane + 64];
  q[lane + 128] = (v2 - mu) * r * w[lane + 128] + b[lane + 128];
  q[lane + 192] = (v3 - mu) * r * w[lane + 192] + b[lane + 192];
}

// MFMA GEMM: out[m][n] = epi(sum_k A[m][k]*Wt[n][k] + bias[n]).
template <int KD, int ND, int ACT, int RES, int OUTB>
__global__ __launch_bounds__(256) void mfma_gemm(const uint16_t* __restrict__ A,
                                                 const uint16_t* __restrict__ Wt,
                                                 const float* __restrict__ bias,
                                                 const float* __restrict__ res,
                                                 float* __restrict__ outf,
                                                 uint16_t* __restrict__ outb, int M) {
  __shared__ uint16_t sA[64][72];
  __shared__ uint16_t sB[64][72];
  int m0 = blockIdx.x * 64, n0 = blockIdx.y * 64;
  int tid = threadIdx.x, lane = tid & 63, wid = tid >> 6;
  int wr = (wid >> 1) * 32, wc = (wid & 1) * 32;
  int lrow = lane & 15, lko = (lane >> 4) * 8;

  f32x4 acc00 = {0.f, 0.f, 0.f, 0.f}, acc01 = acc00, acc10 = acc00, acc11 = acc00;

  for (int k0 = 0; k0 < KD; k0 += 64) {
#pragma unroll
    for (int it = 0; it < 2; ++it) {
      int chunk = tid + it * 256;
      int row = chunk >> 3, kc = (chunk & 7) * 8;
      *(bf16x8*)&sA[row][kc] = *(const bf16x8*)(A + (size_t)(m0 + row) * KD + k0 + kc);
      *(bf16x8*)&sB[row][kc] = *(const bf16x8*)(Wt + (size_t)(n0 + row) * KD + k0 + kc);
    }
    __syncthreads();
#pragma unroll
    for (int kk = 0; kk < 64; kk += 32) {
      bf16x8 a0 = *(const bf16x8*)&sA[wr + lrow][kk + lko];
      bf16x8 a1 = *(const bf16x8*)&sA[wr + 16 + lrow][kk + lko];
      bf16x8 b0 = *(const bf16x8*)&sB[wc + lrow][kk + lko];
      bf16x8 b1 = *(const bf16x8*)&sB[wc + 16 + lrow][kk + lko];
      acc00 = __builtin_amdgcn_mfma_f32_16x16x32_bf16(a0, b0, acc00, 0, 0, 0);
      acc01 = __builtin_amdgcn_mfma_f32_16x16x32_bf16(a0, b1, acc01, 0, 0, 0);
      acc10 = __builtin_amdgcn_mfma_f32_16x16x32_bf16(a1, b0, acc10, 0, 0, 0);
      acc11 = __builtin_amdgcn_mfma_f32_16x16x32_bf16(a1, b1, acc11, 0, 0, 0);
    }
    __syncthreads();
  }

  int rbase = m0 + wr + (lane >> 4) * 4;
  int cb0 = n0 + wc + lrow, cb1 = cb0 + 16;
  float bv0 = bias ? bias[cb0] : 0.f;
  float bv1 = bias ? bias[cb1] : 0.f;
  f32x4 av[2][2] = {{acc00, acc01}, {acc10, acc11}};
#pragma unroll
  for (int mi = 0; mi < 2; ++mi) {
#pragma unroll
    for (int ni = 0; ni < 2; ++ni) {
      int col = ni ? cb1 : cb0;
      float bv = ni ? bv1 : bv0;
#pragma unroll
      for (int j = 0; j < 4; ++j) {
        int row = rbase + mi * 16 + j;
        if (row < M) {
          float a = av[mi][ni][j] + bv;
          if (ACT) a = 0.5f * a * (1.f + erff(a * 0.70710678118654752f));
          if (RES) a += res[(size_t)row * ND + col];
          if (OUTB) outb[(size_t)row * ND + col] = f2bf(a);
          else outf[(size_t)row * ND + col] = a;
        }
      }
    }
  }
}

// ---------------------------------------------------------------------------
// Neighborhood attention via MFMA. Block = (b, head, 8x8 q-tile), 392 blocks.
// Dense 64 q x 224 key (14x14 halo zero-padded) QK^T, masked softmax, PV.
// ---------------------------------------------------------------------------
#define KSWZ(row, colbytes) (((row) * 64 + (colbytes)) ^ (((row) & 7) << 4))

__global__ __launch_bounds__(256) void natten_mfma(const uint16_t* __restrict__ qkv,
                                                   const float* __restrict__ rpb,
                                                   uint16_t* __restrict__ out) {
  __shared__ uint16_t s_k[224 * 32];   // K rows, XOR-swizzled, 14336 B
  __shared__ uint16_t s_vt[32][232];   // V^T [d][key], 14848 B
  __shared__ uint16_t s_p[64][232];    // P  [q][key], 29696 B
  __shared__ float s_rpb[169];

  int tid = threadIdx.x;
  int blk = blockIdx.x;
  int bh = blk & 7, tile = blk >> 3;
  int b = bh >> 2, head = bh & 3;
  int ti = tile / 7, tj = tile % 7;
  int i0 = ti * 8, j0 = tj * 8;
  int rbase = min(max(i0 - 3, 0), 42);
  int cbase = min(max(j0 - 3, 0), 42);

  const bf16x8 bz = {0, 0, 0, 0, 0, 0, 0, 0};
  const f32x4 fz = {0.f, 0.f, 0.f, 0.f};

  // zero-fill K pad rows 196..223
  if (tid < 112)
    *(bf16x8*)((char*)s_k + KSWZ(196 + (tid >> 2), (tid & 3) * 16)) = bz;
  // zero-fill Vt pad cols 196..227
  for (int idx = tid; idx < 1024; idx += 256) s_vt[idx >> 5][196 + (idx & 31)] = 0;
  // stage K (swizzled rows) and V (transposed)
  for (int idx = tid; idx < 784; idx += 256) {
    int pos = idx >> 2, ch = (idx & 3) * 8;
    int r = rbase + pos / 14, c = cbase + pos % 14;
    const uint16_t* base = qkv + ((size_t)(b * 3136 + r * 56 + c)) * 384 + head * 32 + ch;
    bf16x8 kv = *(const bf16x8*)(base + 128);
    bf16x8 vv = *(const bf16x8*)(base + 256);
    *(bf16x8*)((char*)s_k + KSWZ(pos, ch * 2)) = kv;
#pragma unroll
    for (int e = 0; e < 8; ++e) s_vt[ch + e][pos] = (uint16_t)vv[e];
  }
  for (int idx = tid; idx < 169; idx += 256) s_rpb[idx] = rpb[head * 169 + idx];
  __syncthreads();

  int lane = tid & 63, wq = tid >> 6;
  int lc = lane & 15, g = lane >> 4;
  int q0 = wq * 16;

  // Q A-fragment straight from global (row = q0+lc, k-cols g*8..+7)
  {
  }
  int pA = q0 + lc;
  int piA = i0 + (pA >> 3), pjA = j0 + (pA & 7);
  bf16x8 qfrag =
      *(const bf16x8*)(qkv + ((size_t)(b * 3136 + piA * 56 + pjA)) * 384 + head * 32 + g * 8);

  // QK^T: 14 key tiles of 16
  f32x4 S[14];
#pragma unroll
  for (int t = 0; t < 14; ++t) {
    bf16x8 kfrag = *(const bf16x8*)((char*)s_k + KSWZ(t * 16 + lc, g * 16));
    S[t] = __builtin_amdgcn_mfma_f32_16x16x32_bf16(qfrag, kfrag, fz, 0, 0, 0);
  }

  // --- masked softmax. Lane owns S rows rq = g*4+jj (q = q0+rq), col = t*16+lc.
  int qi = wq * 2 + (g >> 1);          // row-coord within image for all 4 jj
  int i = i0 + qi;
  int a = min(max(i - 3, 0), 49) - rbase;  // valid kr in [a, a+6]
  int brc = 6 - (i0 - rbase) - qi;         // bias row = kr + brc
  int bj[4], bcc[4];
#pragma unroll
  for (int jj = 0; jj < 4; ++jj) {
    int qj = 4 * (g & 1) + jj;
    int j = j0 + qj;
    bj[jj] = min(max(j - 3, 0), 49) - cbase;  // valid kc in [bj, bj+6]
    bcc[jj] = 6 - (j0 - cbase) - qj;          // bias col = kc + bcc
  }

  float mx[4] = {-1e30f, -1e30f, -1e30f, -1e30f};
  int kr = (lc >= 14) ? 1 : 0;
  int kc = lc - 14 * kr;
#pragma unroll
  for (int t = 0; t < 14; ++t) {
    bool vr = (kr >= a) && (kr <= a + 6);
    int brrow = (kr + brc) * 13;
#pragma unroll
    for (int jj = 0; jj < 4; ++jj) {
      float sv = S[t][jj] * 0.17677669529663687f;
      bool v = vr && (kc >= bj[jj]) && (kc <= bj[jj] + 6);
      int bidx = v ? (brrow + kc + bcc[jj]) : 0;
      float val = v ? (sv + s_rpb[bidx]) : -1e30f;
      S[t][jj] = val;
      mx[jj] = fmaxf(mx[jj], val);
    }
    // advance key by 16: kr += 1, kc += 2 (wrap)
    kr += 1;
    kc += 2;
    if (kc >= 14) { kc -= 14; kr += 1; }
  }
#pragma unroll
  for (int jj = 0; jj < 4; ++jj) {
#pragma unroll
    for (int off = 1; off < 16; off <<= 1) mx[jj] = fmaxf(mx[jj], __shfl_xor(mx[jj], off, 64));
  }

  float sm[4] = {0.f, 0.f, 0.f, 0.f};
#pragma unroll
  for (int t = 0; t < 14; ++t) {
#pragma unroll
    for (int jj = 0; jj < 4; ++jj) {
      float e = __expf(S[t][jj] - mx[jj]);
      sm[jj] += e;
      s_p[q0 + g * 4 + jj][t * 16 + lc] = f2bf(e);
    }
  }
#pragma unroll
  for (int jj = 0; jj < 4; ++jj) {
#pragma unroll
    for (int off = 1; off < 16; off <<= 1) sm[jj] += __shfl_xor(sm[jj], off, 64);
    sm[jj] = 1.f / sm[jj];
  }

  __syncthreads();  // P writes -> P fragment reads (same wave, but be safe)

  // PV: O(16q x 32d) per wave; A = P rows (q0+lc), B = Vt rows (d = dt*16+lc)
  f32x4 O[2] = {fz, fz};
#pragma unroll
  for (int k7 = 0; k7 < 7; ++k7) {
    bf16x8 pa = *(const bf16x8*)&s_p[q0 + lc][k7 * 32 + g * 8];
#pragma unroll
    for (int dt = 0; dt < 2; ++dt) {
      bf16x8 vb = *(const bf16x8*)&s_vt[dt * 16 + lc][k7 * 32 + g * 8];
      O[dt] = __builtin_amdgcn_mfma_f32_16x16x32_bf16(pa, vb, O[dt], 0, 0, 0);
    }
  }

  // epilogue: O C-layout rows = g*4+jj (match sm), col = dt*16+lc
#pragma unroll
  for (int jj = 0; jj < 4; ++jj) {
    int q = q0 + g * 4 + jj;
    int pi = i0 + (q >> 3), pj = j0 + (q & 7);
    size_t ob = ((size_t)(b * 3136 + pi * 56 + pj)) * 128 + head * 32;
    out[ob + lc] = f2bf(O[0][jj] * sm[jj]);
    out[ob + 16 + lc] = f2bf(O[1][jj] * sm[jj]);
  }
}

// im2col for 3x3 stride-2 pad-1 conv: xbuf f32 -> col bf16 [1600][1152]
__global__ __launch_bounds__(256) void im2col_kernel(const float* __restrict__ x,
                                                     uint16_t* __restrict__ col) {
  int chunk = blockIdx.x * 256 + threadIdx.x;  // 230400 total
  int row = chunk / 144, cc = chunk - row * 144;
  int t = cc * 8, kk = t >> 7, ic = t & 127;
  float v[8] = {0.f, 0.f, 0.f, 0.f, 0.f, 0.f, 0.f, 0.f};
  if (row < 1568) {
    int ow = row % 28, oh = (row / 28) % 28, bb = row / 784;
    int ih = 2 * oh - 1 + kk / 3, iw = 2 * ow - 1 + kk % 3;
    if (ih >= 0 && ih < 56 && iw >= 0 && iw < 56) {
      const float4* p = (const float4*)(x + (size_t)((bb * 56 + ih) * 56 + iw) * 128 + ic);
      float4 p0 = p[0], p1 = p[1];
      v[0] = p0.x; v[1] = p0.y; v[2] = p0.z; v[3] = p0.w;
      v[4] = p1.x; v[5] = p1.y; v[6] = p1.z; v[7] = p1.w;
    }
  }
  union { uint16_t us[8]; bf16x8 vv; } tmp;
#pragma unroll
  for (int i2 = 0; i2 < 8; ++i2) tmp.us[i2] = f2bf(v[i2]);
  *(bf16x8*)(col + (size_t)row * 1152 + t) = tmp.vv;
}

extern "C" void kernel_launch(void* const* d_in, const int* in_sizes, int n_in,
                              void* d_out, int out_size, void* d_ws, size_t ws_size,
                              hipStream_t stream) {
  const float* x    = (const float*)d_in[0];
  const float* n1w  = (const float*)d_in[1];
  const float* n1b  = (const float*)d_in[2];
  const float* qkvw = (const float*)d_in[3];
  const float* qkvb = (const float*)d_in[4];
  const float* rpb  = (const float*)d_in[5];
  const float* pw   = (const float*)d_in[6];
  const float* pb   = (const float*)d_in[7];
  const float* n2w  = (const float*)d_in[8];
  const float* n2b  = (const float*)d_in[9];
  const float* f1w  = (const float*)d_in[10];
  const float* f1b  = (const float*)d_in[11];
  const float* f2w  = (const float*)d_in[12];
  const float* f2b  = (const float*)d_in[13];
  const float* cw   = (const float*)d_in[14];
  const float* dnw  = (const float*)d_in[15];
  const float* dnb  = (const float*)d_in[16];
  float* out = (float*)d_out;

  char* wsb = (char*)d_ws;
  float* xbuf      = (float*)(wsb + 0);           // 3211264 B
  uint16_t* h_b    = (uint16_t*)(wsb + 3211264);  // 1605632 B
  uint16_t* qkv_b  = (uint16_t*)(wsb + 4816896);  // 4816896 B (aliased by col)
  uint16_t* att_b  = (uint16_t*)(wsb + 9633792);  // 1605632 B (aliased by convout)
  uint16_t* hid_b  = (uint16_t*)(wsb + 11239424); // 6422528 B
  uint16_t* wts    = (uint16_t*)(wsb + 17661952); // 1376256 B
  uint16_t* col_b   = qkv_b;
  float*    convout = (float*)att_b;
  uint16_t* qkvwt = wts;            // 2 x 384x128
  uint16_t* pwt   = wts + 98304;    // 2 x 128x128
  uint16_t* f1wt  = wts + 131072;   // 2 x 512x128
  uint16_t* f2wt  = wts + 262144;   // 2 x 128x512
  uint16_t* cwt   = wts + 393216;   // 256x1152

  transpose_w<<<dim3(12, 4), 256, 0, stream>>>(qkvw, qkvwt, 128, 384);
  transpose_w<<<dim3(12, 4), 256, 0, stream>>>(qkvw + 49152, qkvwt + 49152, 128, 384);
  transpose_w<<<dim3(4, 4), 256, 0, stream>>>(pw, pwt, 128, 128);
  transpose_w<<<dim3(4, 4), 256, 0, stream>>>(pw + 16384, pwt + 16384, 128, 128);
  transpose_w<<<dim3(16, 4), 256, 0, stream>>>(f1w, f1wt, 128, 512);
  transpose_w<<<dim3(16, 4), 256, 0, stream>>>(f1w + 65536, f1wt + 65536, 128, 512);
  transpose_w<<<dim3(4, 16), 256, 0, stream>>>(f2w, f2wt, 512, 128);
  transpose_w<<<dim3(4, 16), 256, 0, stream>>>(f2w + 65536, f2wt + 65536, 512, 128);
  transpose_w<<<dim3(8, 36), 256, 0, stream>>>(cw, cwt, 1152, 256);

  for (int i = 0; i < 2; ++i) {
    const float* xin = (i == 0) ? x : xbuf;
    ln_kernel<<<1568, 256, 0, stream>>>(xin, h_b, n1w + i * 128, n1b + i * 128);
    mfma_gemm<128, 384, 0, 0, 1><<<dim3(98, 6), 256, 0, stream>>>(
        h_b, qkvwt + i * 49152, qkvb + i * 384, nullptr, nullptr, qkv_b, 6272);
    natten_mfma<<<392, 256, 0, stream>>>(qkv_b, rpb + i * 676, att_b);
    mfma_gemm<128, 128, 0, 1, 0><<<dim3(98, 2), 256, 0, stream>>>(
        att_b, pwt + i * 16384, pb + i * 128, xin, xbuf, nullptr, 6272);
    ln_kernel<<<1568, 256, 0, stream>>>(xbuf, h_b, n2w + i * 128, n2b + i * 128);
    mfma_gemm<128, 512, 1, 0, 1><<<dim3(98, 8), 256, 0, stream>>>(
        h_b, f1wt + i * 65536, f1b + i * 512, nullptr, nullptr, hid_b, 6272);
    mfma_gemm<512, 128, 0, 1, 0><<<dim3(98, 2), 256, 0, stream>>>(
        hid_b, f2wt + i * 65536, f2b + i * 128, xbuf, xbuf, nullptr, 6272);
  }

  im2col_kernel<<<900, 256, 0, stream>>>(xbuf, col_b);
  mfma_gemm<1152, 256, 0, 0, 0><<<dim3(25, 4), 256, 0, stream>>>(
      col_b, cwt, nullptr, nullptr, convout, nullptr, 1568);
  ln256_kernel<<<392, 256, 0, stream>>>(convout, out, dnw, dnb);
  copy_kernel<<<784, 256, 0, stream>>>((const float4*)xbuf, (float4*)(out + 401408), 200704);
}

// Round 5
// 161.565 us; speedup vs baseline: 2.3952x; 1.0501x over previous
//
#include <hip/hip_runtime.h>
#include <stdint.h>

// ---------------------------------------------------------------------------
// NAT block forward: B=2, H=W=56, C=128, nh=4, hd=32, K=7, depth=2, hidden=512
// Round 5: fusion pass. 13 launches total:
//   prep_weights(1) + 2x[qkv(LN-fused), natten, proj+res, fc1(LN-fused), fc2+res]
//   + implicit-im2col conv GEMM + ln256.
// ---------------------------------------------------------------------------

typedef __attribute__((ext_vector_type(8))) short bf16x8;
typedef __attribute__((ext_vector_type(4))) float f32x4;

__device__ __forceinline__ float bf2f(uint16_t u) {
  union { uint32_t u; float f; } t;
  t.u = (uint32_t)u << 16;
  return t.f;
}
__device__ __forceinline__ uint16_t f2bf(float f) {
  union { float f; uint32_t u; } t;
  t.f = f;
  return (uint16_t)((t.u + 0x7FFFu + ((t.u >> 16) & 1u)) >> 16);
}

// ---------------------------------------------------------------------------
// One-shot weight prep: 9 transpose+bf16 jobs in one launch (672 blocks).
// ---------------------------------------------------------------------------
struct PrepArgs {
  const float* src[9];
  uint16_t* dst[9];
  int K[9], N[9];
  int cum[10];
};

__global__ __launch_bounds__(256) void prep_weights(PrepArgs a) {
  __shared__ float t[32][33];
  int bt = blockIdx.x;
  int j = 0;
#pragma unroll
  for (int u = 0; u < 9; ++u)
    if (bt >= a.cum[u + 1]) j = u + 1;
  int lt = bt - a.cum[j];
  const float* w = a.src[j];
  uint16_t* wt = a.dst[j];
  int K = a.K[j], N = a.N[j];
  int tn = N >> 5;
  int n0 = (lt % tn) * 32, k0 = (lt / tn) * 32;
  int tx = threadIdx.x & 31, ty = threadIdx.x >> 5;
#pragma unroll
  for (int r2 = 0; r2 < 32; r2 += 8)
    t[ty + r2][tx] = w[(size_t)(k0 + ty + r2) * N + n0 + tx];
  __syncthreads();
#pragma unroll
  for (int r2 = 0; r2 < 32; r2 += 8)
    wt[(size_t)(n0 + ty + r2) * K + k0 + tx] = f2bf(t[tx][ty + r2]);
}

// LayerNorm over C=256, fp32 in -> fp32 out (d_out). Wave per pixel.
__global__ __launch_bounds__(256) void ln256_kernel(const float* __restrict__ in,
                                                    float* __restrict__ out,
                                                    const float* __restrict__ w,
                                                    const float* __restrict__ b) {
  int wave = threadIdx.x >> 6, lane = threadIdx.x & 63;
  int pix = blockIdx.x * 4 + wave;
  const float* p = in + (size_t)pix * 256;
  float v0 = p[lane], v1 = p[lane + 64], v2 = p[lane + 128], v3 = p[lane + 192];
  float s = v0 + v1 + v2 + v3;
  float s2 = v0 * v0 + v1 * v1 + v2 * v2 + v3 * v3;
#pragma unroll
  for (int off = 32; off; off >>= 1) {
    s += __shfl_xor(s, off, 64);
    s2 += __shfl_xor(s2, off, 64);
  }
  float mu = s * (1.f / 256.f);
  float var = s2 * (1.f / 256.f) - mu * mu;
  float r = rsqrtf(var + 1e-5f);
  float* q = out + (size_t)pix * 256;
  q[lane] = (v0 - mu) * r * w[lane] + b[lane];
  q[lane + 64] = (v1 - mu) * r * w[lane + 64] + b[lane + 64];
  q[lane + 128] = (v2 - mu) * r * w[lane + 128] + b[lane + 128];
  q[lane + 192] = (v3 - mu) * r * w[lane + 192] + b[lane + 192];
}

// ---------------------------------------------------------------------------
// MFMA GEMM, optionally with LayerNorm fused into A-staging (LNF=1, KD==128).
// out[m][n] = epi(sum_k A[m][k]*Wt[n][k] + bias[n]); epi: GELU / +res; out
// f32 or bf16; optional second f32 output (residual copy-out).
// ---------------------------------------------------------------------------
template <int KD, int ND, int ACT, int RES, int OUTB, int LNF>
__global__ __launch_bounds__(256) void mfma_gemm(
    const uint16_t* __restrict__ A, const float* __restrict__ Af,
    const float* __restrict__ lnw, const float* __restrict__ lnb,
    const uint16_t* __restrict__ Wt, const float* __restrict__ bias,
    const float* __restrict__ res, float* __restrict__ outf,
    uint16_t* __restrict__ outb, float* __restrict__ outf2, int M) {
  constexpr int AP = LNF ? 136 : 72;
  __shared__ uint16_t sA[64][AP];
  __shared__ uint16_t sB[64][AP];
  __shared__ float2 s_red[LNF ? 64 : 1][4];
  __shared__ float2 s_stat[LNF ? 64 : 1];

  int m0 = blockIdx.x * 64, n0 = blockIdx.y * 64;
  int tid = threadIdx.x, lane = tid & 63, wid = tid >> 6;
  int wr = (wid >> 1) * 32, wc = (wid & 1) * 32;
  int lrow = lane & 15, lko = (lane >> 4) * 8;

  f32x4 acc00 = {0.f, 0.f, 0.f, 0.f}, acc01 = acc00, acc10 = acc00, acc11 = acc00;

  if constexpr (LNF) {
    // --- LN-fused A staging (full K=128 in one shot) + B staging ---
    int r = tid >> 2, qt = tid & 3;
    const float4* xr = (const float4*)(Af + (size_t)(m0 + r) * 128 + qt * 32);
    float4 xv[8];
    float s = 0.f, s2 = 0.f;
#pragma unroll
    for (int u = 0; u < 8; ++u) {
      xv[u] = xr[u];
      s += xv[u].x + xv[u].y + xv[u].z + xv[u].w;
      s2 += xv[u].x * xv[u].x + xv[u].y * xv[u].y + xv[u].z * xv[u].z + xv[u].w * xv[u].w;
    }
    s_red[r][qt] = make_float2(s, s2);
#pragma unroll
    for (int it = 0; it < 4; ++it) {
      int chunk = tid + it * 256;
      int row = chunk >> 4, kc = (chunk & 15) * 8;
      *(bf16x8*)&sB[row][kc] = *(const bf16x8*)(Wt + (size_t)(n0 + row) * 128 + kc);
    }
    __syncthreads();
    if (tid < 64) {
      float2 p0 = s_red[tid][0], p1 = s_red[tid][1], p2 = s_red[tid][2], p3 = s_red[tid][3];
      float S = p0.x + p1.x + p2.x + p3.x, S2 = p0.y + p1.y + p2.y + p3.y;
      float mu = S * (1.f / 128.f);
      float var = S2 * (1.f / 128.f) - mu * mu;
      s_stat[tid] = make_float2(mu, rsqrtf(var + 1e-5f));
    }
    __syncthreads();
    float mu = s_stat[r].x, rstd = s_stat[r].y;
    const float* lw = lnw + qt * 32;
    const float* lb = lnb + qt * 32;
    union { uint16_t us[8]; bf16x8 v; } tq[4];
#pragma unroll
    for (int u = 0; u < 8; ++u) {
      tq[u >> 1].us[(u & 1) * 4 + 0] = f2bf((xv[u].x - mu) * rstd * lw[u * 4 + 0] + lb[u * 4 + 0]);
      tq[u >> 1].us[(u & 1) * 4 + 1] = f2bf((xv[u].y - mu) * rstd * lw[u * 4 + 1] + lb[u * 4 + 1]);
      tq[u >> 1].us[(u & 1) * 4 + 2] = f2bf((xv[u].z - mu) * rstd * lw[u * 4 + 2] + lb[u * 4 + 2]);
      tq[u >> 1].us[(u & 1) * 4 + 3] = f2bf((xv[u].w - mu) * rstd * lw[u * 4 + 3] + lb[u * 4 + 3]);
    }
#pragma unroll
    for (int q2 = 0; q2 < 4; ++q2) *(bf16x8*)&sA[r][qt * 32 + q2 * 8] = tq[q2].v;
    __syncthreads();
#pragma unroll
    for (int kk = 0; kk < 128; kk += 32) {
      bf16x8 a0 = *(const bf16x8*)&sA[wr + lrow][kk + lko];
      bf16x8 a1 = *(const bf16x8*)&sA[wr + 16 + lrow][kk + lko];
      bf16x8 b0 = *(const bf16x8*)&sB[wc + lrow][kk + lko];
      bf16x8 b1 = *(const bf16x8*)&sB[wc + 16 + lrow][kk + lko];
      acc00 = __builtin_amdgcn_mfma_f32_16x16x32_bf16(a0, b0, acc00, 0, 0, 0);
      acc01 = __builtin_amdgcn_mfma_f32_16x16x32_bf16(a0, b1, acc01, 0, 0, 0);
      acc10 = __builtin_amdgcn_mfma_f32_16x16x32_bf16(a1, b0, acc10, 0, 0, 0);
      acc11 = __builtin_amdgcn_mfma_f32_16x16x32_bf16(a1, b1, acc11, 0, 0, 0);
    }
  } else {
    for (int k0 = 0; k0 < KD; k0 += 64) {
#pragma unroll
      for (int it = 0; it < 2; ++it) {
        int chunk = tid + it * 256;
        int row = chunk >> 3, kc = (chunk & 7) * 8;
        *(bf16x8*)&sA[row][kc] = *(const bf16x8*)(A + (size_t)(m0 + row) * KD + k0 + kc);
        *(bf16x8*)&sB[row][kc] = *(const bf16x8*)(Wt + (size_t)(n0 + row) * KD + k0 + kc);
      }
      __syncthreads();
#pragma unroll
      for (int kk = 0; kk < 64; kk += 32) {
        bf16x8 a0 = *(const bf16x8*)&sA[wr + lrow][kk + lko];
        bf16x8 a1 = *(const bf16x8*)&sA[wr + 16 + lrow][kk + lko];
        bf16x8 b0 = *(const bf16x8*)&sB[wc + lrow][kk + lko];
        bf16x8 b1 = *(const bf16x8*)&sB[wc + 16 + lrow][kk + lko];
        acc00 = __builtin_amdgcn_mfma_f32_16x16x32_bf16(a0, b0, acc00, 0, 0, 0);
        acc01 = __builtin_amdgcn_mfma_f32_16x16x32_bf16(a0, b1, acc01, 0, 0, 0);
        acc10 = __builtin_amdgcn_mfma_f32_16x16x32_bf16(a1, b0, acc10, 0, 0, 0);
        acc11 = __builtin_amdgcn_mfma_f32_16x16x32_bf16(a1, b1, acc11, 0, 0, 0);
      }
      __syncthreads();
    }
  }

  // epilogue. C/D layout: col = lane&15, row = (lane>>4)*4 + j
  int rbase = m0 + wr + (lane >> 4) * 4;
  int cb0 = n0 + wc + lrow, cb1 = cb0 + 16;
  float bv0 = bias ? bias[cb0] : 0.f;
  float bv1 = bias ? bias[cb1] : 0.f;
  f32x4 av[2][2] = {{acc00, acc01}, {acc10, acc11}};
#pragma unroll
  for (int mi = 0; mi < 2; ++mi) {
#pragma unroll
    for (int ni = 0; ni < 2; ++ni) {
      int col = ni ? cb1 : cb0;
      float bv = ni ? bv1 : bv0;
#pragma unroll
      for (int j = 0; j < 4; ++j) {
        int row = rbase + mi * 16 + j;
        if (row < M) {
          float a = av[mi][ni][j] + bv;
          if (ACT) a = 0.5f * a * (1.f + erff(a * 0.70710678118654752f));
          if (RES) a += res[(size_t)row * ND + col];
          if (OUTB) {
            outb[(size_t)row * ND + col] = f2bf(a);
          } else {
            outf[(size_t)row * ND + col] = a;
            if (outf2) outf2[(size_t)row * ND + col] = a;
          }
        }
      }
    }
  }
}

// ---------------------------------------------------------------------------
// Neighborhood attention via MFMA. Block = (b, head, 8x8 q-tile), 392 blocks.
// ---------------------------------------------------------------------------
#define KSWZ(row, colbytes) (((row) * 64 + (colbytes)) ^ (((row) & 7) << 4))

__global__ __launch_bounds__(256) void natten_mfma(const uint16_t* __restrict__ qkv,
                                                   const float* __restrict__ rpb,
                                                   uint16_t* __restrict__ out) {
  __shared__ uint16_t s_k[224 * 32];
  __shared__ uint16_t s_vt[32][232];
  __shared__ uint16_t s_p[64][232];
  __shared__ float s_rpb[169];

  int tid = threadIdx.x;
  int blk = blockIdx.x;
  int bh = blk & 7, tile = blk >> 3;
  int b = bh >> 2, head = bh & 3;
  int ti = tile / 7, tj = tile % 7;
  int i0 = ti * 8, j0 = tj * 8;
  int rbase = min(max(i0 - 3, 0), 42);
  int cbase = min(max(j0 - 3, 0), 42);

  const bf16x8 bz = {0, 0, 0, 0, 0, 0, 0, 0};
  const f32x4 fz = {0.f, 0.f, 0.f, 0.f};

  if (tid < 112)
    *(bf16x8*)((char*)s_k + KSWZ(196 + (tid >> 2), (tid & 3) * 16)) = bz;
  for (int idx = tid; idx < 1024; idx += 256) s_vt[idx >> 5][196 + (idx & 31)] = 0;
  for (int idx = tid; idx < 784; idx += 256) {
    int pos = idx >> 2, ch = (idx & 3) * 8;
    int r = rbase + pos / 14, c = cbase + pos % 14;
    const uint16_t* base = qkv + ((size_t)(b * 3136 + r * 56 + c)) * 384 + head * 32 + ch;
    bf16x8 kv = *(const bf16x8*)(base + 128);
    bf16x8 vv = *(const bf16x8*)(base + 256);
    *(bf16x8*)((char*)s_k + KSWZ(pos, ch * 2)) = kv;
#pragma unroll
    for (int e = 0; e < 8; ++e) s_vt[ch + e][pos] = (uint16_t)vv[e];
  }
  for (int idx = tid; idx < 169; idx += 256) s_rpb[idx] = rpb[head * 169 + idx];
  __syncthreads();

  int lane = tid & 63, wq = tid >> 6;
  int lc = lane & 15, g = lane >> 4;
  int q0 = wq * 16;

  int pA = q0 + lc;
  int piA = i0 + (pA >> 3), pjA = j0 + (pA & 7);
  bf16x8 qfrag =
      *(const bf16x8*)(qkv + ((size_t)(b * 3136 + piA * 56 + pjA)) * 384 + head * 32 + g * 8);

  f32x4 S[14];
#pragma unroll
  for (int t = 0; t < 14; ++t) {
    bf16x8 kfrag = *(const bf16x8*)((char*)s_k + KSWZ(t * 16 + lc, g * 16));
    S[t] = __builtin_amdgcn_mfma_f32_16x16x32_bf16(qfrag, kfrag, fz, 0, 0, 0);
  }

  int qi = wq * 2 + (g >> 1);
  int i = i0 + qi;
  int a = min(max(i - 3, 0), 49) - rbase;
  int brc = 6 - (i0 - rbase) - qi;
  int bj[4], bcc[4];
#pragma unroll
  for (int jj = 0; jj < 4; ++jj) {
    int qj = 4 * (g & 1) + jj;
    int j = j0 + qj;
    bj[jj] = min(max(j - 3, 0), 49) - cbase;
    bcc[jj] = 6 - (j0 - cbase) - qj;
  }

  float mx[4] = {-1e30f, -1e30f, -1e30f, -1e30f};
  int kr = (lc >= 14) ? 1 : 0;
  int kc = lc - 14 * kr;
#pragma unroll
  for (int t = 0; t < 14; ++t) {
    bool vr = (kr >= a) && (kr <= a + 6);
    int brrow = (kr + brc) * 13;
#pragma unroll
    for (int jj = 0; jj < 4; ++jj) {
      float sv = S[t][jj] * 0.17677669529663687f;
      bool v = vr && (kc >= bj[jj]) && (kc <= bj[jj] + 6);
      int bidx = v ? (brrow + kc + bcc[jj]) : 0;
      float val = v ? (sv + s_rpb[bidx]) : -1e30f;
      S[t][jj] = val;
      mx[jj] = fmaxf(mx[jj], val);
    }
    kr += 1;
    kc += 2;
    if (kc >= 14) { kc -= 14; kr += 1; }
  }
#pragma unroll
  for (int jj = 0; jj < 4; ++jj) {
#pragma unroll
    for (int off = 1; off < 16; off <<= 1) mx[jj] = fmaxf(mx[jj], __shfl_xor(mx[jj], off, 64));
  }

  float sm[4] = {0.f, 0.f, 0.f, 0.f};
#pragma unroll
  for (int t = 0; t < 14; ++t) {
#pragma unroll
    for (int jj = 0; jj < 4; ++jj) {
      float e = __expf(S[t][jj] - mx[jj]);
      sm[jj] += e;
      s_p[q0 + g * 4 + jj][t * 16 + lc] = f2bf(e);
    }
  }
#pragma unroll
  for (int jj = 0; jj < 4; ++jj) {
#pragma unroll
    for (int off = 1; off < 16; off <<= 1) sm[jj] += __shfl_xor(sm[jj], off, 64);
    sm[jj] = 1.f / sm[jj];
  }

  __syncthreads();

  f32x4 O[2] = {fz, fz};
#pragma unroll
  for (int k7 = 0; k7 < 7; ++k7) {
    bf16x8 pa = *(const bf16x8*)&s_p[q0 + lc][k7 * 32 + g * 8];
#pragma unroll
    for (int dt = 0; dt < 2; ++dt) {
      bf16x8 vb = *(const bf16x8*)&s_vt[dt * 16 + lc][k7 * 32 + g * 8];
      O[dt] = __builtin_amdgcn_mfma_f32_16x16x32_bf16(pa, vb, O[dt], 0, 0, 0);
    }
  }

#pragma unroll
  for (int jj = 0; jj < 4; ++jj) {
    int q = q0 + g * 4 + jj;
    int pi = i0 + (q >> 3), pj = j0 + (q & 7);
    size_t ob = ((size_t)(b * 3136 + pi * 56 + pj)) * 128 + head * 32;
    out[ob + lc] = f2bf(O[0][jj] * sm[jj]);
    out[ob + 16 + lc] = f2bf(O[1][jj] * sm[jj]);
  }
}

// ---------------------------------------------------------------------------
// Implicit-im2col conv GEMM: 3x3 s2 p1, 128->256. M=1568, K=1152, N=256.
// Grid (25,4), 64x64 tiles. A staged from xbuf f32 on the fly.
// ---------------------------------------------------------------------------
__global__ __launch_bounds__(256) void conv_gemm(const float* __restrict__ x,
                                                 const uint16_t* __restrict__ Wt,
                                                 float* __restrict__ out) {
  __shared__ uint16_t sA[64][72];
  __shared__ uint16_t sB[64][72];
  int m0 = blockIdx.x * 64, n0 = blockIdx.y * 64;
  int tid = threadIdx.x, lane = tid & 63, wid = tid >> 6;
  int wr = (wid >> 1) * 32, wc = (wid & 1) * 32;
  int lrow = lane & 15, lko = (lane >> 4) * 8;

  f32x4 acc00 = {0.f, 0.f, 0.f, 0.f}, acc01 = acc00, acc10 = acc00, acc11 = acc00;

  int r = tid >> 2, c0 = (tid & 3) * 16;
  int opix = m0 + r;
  bool rowok = opix < 1568;
  int ow = opix % 28, oh = (opix / 28) % 28, bb = opix / 784;

#pragma unroll
  for (int ks = 0; ks < 18; ++ks) {
    int kk = ks >> 1, ic0 = (ks & 1) * 64;
    int kh = kk / 3, kw = kk - kh * 3;
    int ih = 2 * oh - 1 + kh, iw = 2 * ow - 1 + kw;
    float4 v0 = {0.f, 0.f, 0.f, 0.f}, v1 = v0, v2 = v0, v3 = v0;
    if (rowok && ih >= 0 && ih < 56 && iw >= 0 && iw < 56) {
      const float4* p = (const float4*)(x + (size_t)((bb * 56 + ih) * 56 + iw) * 128 + ic0 + c0);
      v0 = p[0]; v1 = p[1]; v2 = p[2]; v3 = p[3];
    }
    union { uint16_t us[8]; bf16x8 v; } ta, tb;
    ta.us[0] = f2bf(v0.x); ta.us[1] = f2bf(v0.y); ta.us[2] = f2bf(v0.z); ta.us[3] = f2bf(v0.w);
    ta.us[4] = f2bf(v1.x); ta.us[5] = f2bf(v1.y); ta.us[6] = f2bf(v1.z); ta.us[7] = f2bf(v1.w);
    tb.us[0] = f2bf(v2.x); tb.us[1] = f2bf(v2.y); tb.us[2] = f2bf(v2.z); tb.us[3] = f2bf(v2.w);
    tb.us[4] = f2bf(v3.x); tb.us[5] = f2bf(v3.y); tb.us[6] = f2bf(v3.z); tb.us[7] = f2bf(v3.w);
    *(bf16x8*)&sA[r][c0] = ta.v;
    *(bf16x8*)&sA[r][c0 + 8] = tb.v;
#pragma unroll
    for (int it = 0; it < 2; ++it) {
      int chunk = tid + it * 256;
      int row = chunk >> 3, kc = (chunk & 7) * 8;
      *(bf16x8*)&sB[row][kc] = *(const bf16x8*)(Wt + (size_t)(n0 + row) * 1152 + ks * 64 + kc);
    }
    __syncthreads();
#pragma unroll
    for (int kk2 = 0; kk2 < 64; kk2 += 32) {
      bf16x8 a0 = *(const bf16x8*)&sA[wr + lrow][kk2 + lko];
      bf16x8 a1 = *(const bf16x8*)&sA[wr + 16 + lrow][kk2 + lko];
      bf16x8 b0 = *(const bf16x8*)&sB[wc + lrow][kk2 + lko];
      bf16x8 b1 = *(const bf16x8*)&sB[wc + 16 + lrow][kk2 + lko];
      acc00 = __builtin_amdgcn_mfma_f32_16x16x32_bf16(a0, b0, acc00, 0, 0, 0);
      acc01 = __builtin_amdgcn_mfma_f32_16x16x32_bf16(a0, b1, acc01, 0, 0, 0);
      acc10 = __builtin_amdgcn_mfma_f32_16x16x32_bf16(a1, b0, acc10, 0, 0, 0);
      acc11 = __builtin_amdgcn_mfma_f32_16x16x32_bf16(a1, b1, acc11, 0, 0, 0);
    }
    __syncthreads();
  }

  int rbase = m0 + wr + (lane >> 4) * 4;
  int cb0 = n0 + wc + lrow, cb1 = cb0 + 16;
  f32x4 av[2][2] = {{acc00, acc01}, {acc10, acc11}};
#pragma unroll
  for (int mi = 0; mi < 2; ++mi) {
#pragma unroll
    for (int ni = 0; ni < 2; ++ni) {
      int col = ni ? cb1 : cb0;
#pragma unroll
      for (int j = 0; j < 4; ++j) {
        int row = rbase + mi * 16 + j;
        if (row < 1568) out[(size_t)row * 256 + col] = av[mi][ni][j];
      }
    }
  }
}

extern "C" void kernel_launch(void* const* d_in, const int* in_sizes, int n_in,
                              void* d_out, int out_size, void* d_ws, size_t ws_size,
                              hipStream_t stream) {
  const float* x    = (const float*)d_in[0];
  const float* n1w  = (const float*)d_in[1];
  const float* n1b  = (const float*)d_in[2];
  const float* qkvw = (const float*)d_in[3];
  const float* qkvb = (const float*)d_in[4];
  const float* rpb  = (const float*)d_in[5];
  const float* pw   = (const float*)d_in[6];
  const float* pb   = (const float*)d_in[7];
  const float* n2w  = (const float*)d_in[8];
  const float* n2b  = (const float*)d_in[9];
  const float* f1w  = (const float*)d_in[10];
  const float* f1b  = (const float*)d_in[11];
  const float* f2w  = (const float*)d_in[12];
  const float* f2b  = (const float*)d_in[13];
  const float* cw   = (const float*)d_in[14];
  const float* dnw  = (const float*)d_in[15];
  const float* dnb  = (const float*)d_in[16];
  float* out = (float*)d_out;

  char* wsb = (char*)d_ws;
  float*    xbuf    = (float*)(wsb + 0);          // 3211264 B
  uint16_t* qkv_b   = (uint16_t*)(wsb + 3211264); // 4816896 B
  uint16_t* att_b   = (uint16_t*)(wsb + 8028160); // 1605632 B
  uint16_t* hid_b   = (uint16_t*)(wsb + 9633792); // 6422528 B
  float*    convout = (float*)(wsb + 16056320);   // 1605632 B
  uint16_t* wts     = (uint16_t*)(wsb + 17661952);// 1376256 B
  uint16_t* qkvwt = wts;            // 2 x 384x128
  uint16_t* pwt   = wts + 98304;    // 2 x 128x128
  uint16_t* f1wt  = wts + 131072;   // 2 x 512x128
  uint16_t* f2wt  = wts + 262144;   // 2 x 128x512
  uint16_t* cwt   = wts + 393216;   // 256x1152

  PrepArgs pa;
  pa.src[0] = qkvw;         pa.dst[0] = qkvwt;          pa.K[0] = 128; pa.N[0] = 384;
  pa.src[1] = qkvw + 49152; pa.dst[1] = qkvwt + 49152;  pa.K[1] = 128; pa.N[1] = 384;
  pa.src[2] = pw;           pa.dst[2] = pwt;            pa.K[2] = 128; pa.N[2] = 128;
  pa.src[3] = pw + 16384;   pa.dst[3] = pwt + 16384;    pa.K[3] = 128; pa.N[3] = 128;
  pa.src[4] = f1w;          pa.dst[4] = f1wt;           pa.K[4] = 128; pa.N[4] = 512;
  pa.src[5] = f1w + 65536;  pa.dst[5] = f1wt + 65536;   pa.K[5] = 128; pa.N[5] = 512;
  pa.src[6] = f2w;          pa.dst[6] = f2wt;           pa.K[6] = 512; pa.N[6] = 128;
  pa.src[7] = f2w + 65536;  pa.dst[7] = f2wt + 65536;   pa.K[7] = 512; pa.N[7] = 128;
  pa.src[8] = cw;           pa.dst[8] = cwt;            pa.K[8] = 1152; pa.N[8] = 256;
  int cums[10] = {0, 48, 96, 112, 128, 192, 256, 320, 384, 672};
  for (int u = 0; u < 10; ++u) pa.cum[u] = cums[u];
  prep_weights<<<672, 256, 0, stream>>>(pa);

  for (int i = 0; i < 2; ++i) {
    const float* xin = (i == 0) ? x : xbuf;
    // qkv GEMM with LN1 fused into A-staging
    mfma_gemm<128, 384, 0, 0, 1, 1><<<dim3(98, 6), 256, 0, stream>>>(
        nullptr, xin, n1w + i * 128, n1b + i * 128, qkvwt + i * 49152, qkvb + i * 384,
        nullptr, nullptr, qkv_b, nullptr, 6272);
    natten_mfma<<<392, 256, 0, stream>>>(qkv_b, rpb + i * 676, att_b);
    // proj + residual
    mfma_gemm<128, 128, 0, 1, 0, 0><<<dim3(98, 2), 256, 0, stream>>>(
        att_b, nullptr, nullptr, nullptr, pwt + i * 16384, pb + i * 128,
        xin, xbuf, nullptr, nullptr, 6272);
    // fc1 with LN2 fused, GELU
    mfma_gemm<128, 512, 1, 0, 1, 1><<<dim3(98, 8), 256, 0, stream>>>(
        nullptr, xbuf, n2w + i * 128, n2b + i * 128, f1wt + i * 65536, f1b + i * 512,
        nullptr, nullptr, hid_b, nullptr, 6272);
    // fc2 + residual (layer 1 also writes the x-output copy)
    mfma_gemm<512, 128, 0, 1, 0, 0><<<dim3(98, 2), 256, 0, stream>>>(
        hid_b, nullptr, nullptr, nullptr, f2wt + i * 65536, f2b + i * 128,
        xbuf, xbuf, nullptr, (i == 1) ? (out + 401408) : nullptr, 6272);
  }

  conv_gemm<<<dim3(25, 4), 256, 0, stream>>>(xbuf, cwt, convout);
  ln256_kernel<<<392, 256, 0, stream>>>(convout, out, dnw, dnb);
}

// Round 6
// 151.813 us; speedup vs baseline: 2.5490x; 1.0642x over previous
//
#include <hip/hip_runtime.h>
#include <stdint.h>

// ---------------------------------------------------------------------------
// NAT block forward: B=2, H=W=56, C=128, nh=4, hd=32, K=7, depth=2, hidden=512
// Round 6: GEMM internals — full-K single-stage, LDS-routed coalesced epilogue,
// shuffle-based fused LN. 13 launches (same structure as round 5).
// ---------------------------------------------------------------------------

typedef __attribute__((ext_vector_type(8))) short bf16x8;
typedef __attribute__((ext_vector_type(4))) float f32x4;

__device__ __forceinline__ float bf2f(uint16_t u) {
  union { uint32_t u; float f; } t;
  t.u = (uint32_t)u << 16;
  return t.f;
}
__device__ __forceinline__ uint16_t f2bf(float f) {
  union { float f; uint32_t u; } t;
  t.f = f;
  return (uint16_t)((t.u + 0x7FFFu + ((t.u >> 16) & 1u)) >> 16);
}

// ---------------------------------------------------------------------------
// One-shot weight prep: 9 transpose+bf16 jobs in one launch (672 blocks).
// ---------------------------------------------------------------------------
struct PrepArgs {
  const float* src[9];
  uint16_t* dst[9];
  int K[9], N[9];
  int cum[10];
};

__global__ __launch_bounds__(256) void prep_weights(PrepArgs a) {
  __shared__ float t[32][33];
  int bt = blockIdx.x;
  int j = 0;
#pragma unroll
  for (int u = 0; u < 9; ++u)
    if (bt >= a.cum[u + 1]) j = u + 1;
  int lt = bt - a.cum[j];
  const float* w = a.src[j];
  uint16_t* wt = a.dst[j];
  int K = a.K[j], N = a.N[j];
  int tn = N >> 5;
  int n0 = (lt % tn) * 32, k0 = (lt / tn) * 32;
  int tx = threadIdx.x & 31, ty = threadIdx.x >> 5;
#pragma unroll
  for (int r2 = 0; r2 < 32; r2 += 8)
    t[ty + r2][tx] = w[(size_t)(k0 + ty + r2) * N + n0 + tx];
  __syncthreads();
#pragma unroll
  for (int r2 = 0; r2 < 32; r2 += 8)
    wt[(size_t)(n0 + ty + r2) * K + k0 + tx] = f2bf(t[tx][ty + r2]);
}

// LayerNorm over C=256, fp32 in -> fp32 out (d_out). Wave per pixel.
__global__ __launch_bounds__(256) void ln256_kernel(const float* __restrict__ in,
                                                    float* __restrict__ out,
                                                    const float* __restrict__ w,
                                                    const float* __restrict__ b) {
  int wave = threadIdx.x >> 6, lane = threadIdx.x & 63;
  int pix = blockIdx.x * 4 + wave;
  const float* p = in + (size_t)pix * 256;
  float v0 = p[lane], v1 = p[lane + 64], v2 = p[lane + 128], v3 = p[lane + 192];
  float s = v0 + v1 + v2 + v3;
  float s2 = v0 * v0 + v1 * v1 + v2 * v2 + v3 * v3;
#pragma unroll
  for (int off = 32; off; off >>= 1) {
    s += __shfl_xor(s, off, 64);
    s2 += __shfl_xor(s2, off, 64);
  }
  float mu = s * (1.f / 256.f);
  float var = s2 * (1.f / 256.f) - mu * mu;
  float r = rsqrtf(var + 1e-5f);
  float* q = out + (size_t)pix * 256;
  q[lane] = (v0 - mu) * r * w[lane] + b[lane];
  q[lane + 64] = (v1 - mu) * r * w[lane + 64] + b[lane + 64];
  q[lane + 128] = (v2 - mu) * r * w[lane + 128] + b[lane + 128];
  q[lane + 192] = (v3 - mu) * r * w[lane + 192] + b[lane + 192];
}

// ---------------------------------------------------------------------------
// MFMA GEMM. 64x64 tile, 4 waves (2x2), wave = 32x32.
// KD=128: single full-K stage, one barrier, 16 MFMA/wave.
// KD=512: 4 chunks of 128. LN fused into A-staging when LNF=1 (KD==128).
// Epilogue routed through LDS for coalesced RES reads / output stores.
// ---------------------------------------------------------------------------
template <int KD, int ND, int ACT, int RES, int OUTB, int LNF>
__global__ __launch_bounds__(256) void mfma_gemm(
    const uint16_t* __restrict__ A, const float* __restrict__ Af,
    const float* __restrict__ lnw, const float* __restrict__ lnb,
    const uint16_t* __restrict__ Wt, const float* __restrict__ bias,
    const float* __restrict__ res, float* __restrict__ outf,
    uint16_t* __restrict__ outb, float* __restrict__ outf2, int M) {
  __shared__ __align__(16) char smem[34816];  // sA[64][136] | sB[64][136]
  uint16_t(*sA)[136] = (uint16_t(*)[136])smem;
  uint16_t(*sB)[136] = (uint16_t(*)[136])(smem + 17408);
  float(*sC)[68] = (float(*)[68])smem;  // epilogue alias (17408 B)

  int m0 = blockIdx.x * 64, n0 = blockIdx.y * 64;
  int tid = threadIdx.x, lane = tid & 63, wid = tid >> 6;
  int wr = (wid >> 1) * 32, wc = (wid & 1) * 32;
  int lrow = lane & 15, lc = lane & 15, g = lane >> 4;
  int lko = g * 8;

  f32x4 acc00 = {0.f, 0.f, 0.f, 0.f}, acc01 = acc00, acc10 = acc00, acc11 = acc00;

  if constexpr (LNF) {
    // LN-fused A staging: quad (4 threads) per row, shuffle stats.
    int r = tid >> 2, qt = tid & 3;
    const float4* xr = (const float4*)(Af + (size_t)(m0 + r) * 128 + qt * 32);
    float4 xv[8];
    float s = 0.f, s2 = 0.f;
#pragma unroll
    for (int u = 0; u < 8; ++u) {
      xv[u] = xr[u];
      s += xv[u].x + xv[u].y + xv[u].z + xv[u].w;
      s2 += xv[u].x * xv[u].x + xv[u].y * xv[u].y + xv[u].z * xv[u].z + xv[u].w * xv[u].w;
    }
    s += __shfl_xor(s, 1, 64);
    s += __shfl_xor(s, 2, 64);
    s2 += __shfl_xor(s2, 1, 64);
    s2 += __shfl_xor(s2, 2, 64);
    float mu = s * (1.f / 128.f);
    float var = s2 * (1.f / 128.f) - mu * mu;
    float rstd = rsqrtf(var + 1e-5f);
    const float* lw = lnw + qt * 32;
    const float* lb = lnb + qt * 32;
    union { uint16_t us[8]; bf16x8 v; } tq[4];
#pragma unroll
    for (int u = 0; u < 8; ++u) {
      tq[u >> 1].us[(u & 1) * 4 + 0] = f2bf((xv[u].x - mu) * rstd * lw[u * 4 + 0] + lb[u * 4 + 0]);
      tq[u >> 1].us[(u & 1) * 4 + 1] = f2bf((xv[u].y - mu) * rstd * lw[u * 4 + 1] + lb[u * 4 + 1]);
      tq[u >> 1].us[(u & 1) * 4 + 2] = f2bf((xv[u].z - mu) * rstd * lw[u * 4 + 2] + lb[u * 4 + 2]);
      tq[u >> 1].us[(u & 1) * 4 + 3] = f2bf((xv[u].w - mu) * rstd * lw[u * 4 + 3] + lb[u * 4 + 3]);
    }
#pragma unroll
    for (int q2 = 0; q2 < 4; ++q2) *(bf16x8*)&sA[r][qt * 32 + q2 * 8] = tq[q2].v;
#pragma unroll
    for (int it = 0; it < 4; ++it) {
      int chunk = tid + it * 256;
      int row = chunk >> 4, kc = (chunk & 15) * 8;
      *(bf16x8*)&sB[row][kc] = *(const bf16x8*)(Wt + (size_t)(n0 + row) * 128 + kc);
    }
    __syncthreads();
#pragma unroll
    for (int kk = 0; kk < 128; kk += 32) {
      bf16x8 a0 = *(const bf16x8*)&sA[wr + lrow][kk + lko];
      bf16x8 a1 = *(const bf16x8*)&sA[wr + 16 + lrow][kk + lko];
      bf16x8 b0 = *(const bf16x8*)&sB[wc + lrow][kk + lko];
      bf16x8 b1 = *(const bf16x8*)&sB[wc + 16 + lrow][kk + lko];
      acc00 = __builtin_amdgcn_mfma_f32_16x16x32_bf16(a0, b0, acc00, 0, 0, 0);
      acc01 = __builtin_amdgcn_mfma_f32_16x16x32_bf16(a0, b1, acc01, 0, 0, 0);
      acc10 = __builtin_amdgcn_mfma_f32_16x16x32_bf16(a1, b0, acc10, 0, 0, 0);
      acc11 = __builtin_amdgcn_mfma_f32_16x16x32_bf16(a1, b1, acc11, 0, 0, 0);
    }
    __syncthreads();
  } else {
    constexpr int NCH = KD / 128;
    for (int c = 0; c < NCH; ++c) {
#pragma unroll
      for (int it = 0; it < 4; ++it) {
        int chunk = tid + it * 256;
        int row = chunk >> 4, kc = (chunk & 15) * 8;
        *(bf16x8*)&sA[row][kc] =
            *(const bf16x8*)(A + (size_t)(m0 + row) * KD + c * 128 + kc);
        *(bf16x8*)&sB[row][kc] =
            *(const bf16x8*)(Wt + (size_t)(n0 + row) * KD + c * 128 + kc);
      }
      __syncthreads();
#pragma unroll
      for (int kk = 0; kk < 128; kk += 32) {
        bf16x8 a0 = *(const bf16x8*)&sA[wr + lrow][kk + lko];
        bf16x8 a1 = *(const bf16x8*)&sA[wr + 16 + lrow][kk + lko];
        bf16x8 b0 = *(const bf16x8*)&sB[wc + lrow][kk + lko];
        bf16x8 b1 = *(const bf16x8*)&sB[wc + 16 + lrow][kk + lko];
        acc00 = __builtin_amdgcn_mfma_f32_16x16x32_bf16(a0, b0, acc00, 0, 0, 0);
        acc01 = __builtin_amdgcn_mfma_f32_16x16x32_bf16(a0, b1, acc01, 0, 0, 0);
        acc10 = __builtin_amdgcn_mfma_f32_16x16x32_bf16(a1, b0, acc10, 0, 0, 0);
        acc11 = __builtin_amdgcn_mfma_f32_16x16x32_bf16(a1, b1, acc11, 0, 0, 0);
      }
      __syncthreads();
    }
  }

  // ---- epilogue: acc(+bias,+GELU) -> sC -> coalesced RES/store ----
  {
    float bv0 = bias ? bias[n0 + wc + lc] : 0.f;
    float bv1 = bias ? bias[n0 + wc + lc + 16] : 0.f;
    f32x4 av[2][2] = {{acc00, acc01}, {acc10, acc11}};
#pragma unroll
    for (int mi = 0; mi < 2; ++mi) {
#pragma unroll
      for (int ni = 0; ni < 2; ++ni) {
        float bv = ni ? bv1 : bv0;
#pragma unroll
        for (int j = 0; j < 4; ++j) {
          float a = av[mi][ni][j] + bv;
          if (ACT) a = 0.5f * a * (1.f + erff(a * 0.70710678118654752f));
          sC[wr + mi * 16 + g * 4 + j][wc + ni * 16 + lc] = a;
        }
      }
    }
    __syncthreads();
    int r = tid >> 2, cs = (tid & 3) * 16;
    int grow = m0 + r;
    if (grow < M) {
      const float4* cp = (const float4*)&sC[r][cs];
      float4 c4[4] = {cp[0], cp[1], cp[2], cp[3]};
      if (RES) {
        const float4* rp = (const float4*)(res + (size_t)grow * ND + n0 + cs);
#pragma unroll
        for (int u = 0; u < 4; ++u) {
          float4 rv = rp[u];
          c4[u].x += rv.x; c4[u].y += rv.y; c4[u].z += rv.z; c4[u].w += rv.w;
        }
      }
      if (OUTB) {
        union { uint16_t us[16]; bf16x8 v[2]; } t;
#pragma unroll
        for (int u = 0; u < 4; ++u) {
          t.us[u * 4 + 0] = f2bf(c4[u].x);
          t.us[u * 4 + 1] = f2bf(c4[u].y);
          t.us[u * 4 + 2] = f2bf(c4[u].z);
          t.us[u * 4 + 3] = f2bf(c4[u].w);
        }
        bf16x8* op = (bf16x8*)(outb + (size_t)grow * ND + n0 + cs);
        op[0] = t.v[0];
        op[1] = t.v[1];
      } else {
        float4* op = (float4*)(outf + (size_t)grow * ND + n0 + cs);
#pragma unroll
        for (int u = 0; u < 4; ++u) op[u] = c4[u];
        if (outf2) {
          float4* op2 = (float4*)(outf2 + (size_t)grow * ND + n0 + cs);
#pragma unroll
          for (int u = 0; u < 4; ++u) op2[u] = c4[u];
        }
      }
    }
  }
}

// ---------------------------------------------------------------------------
// Neighborhood attention via MFMA. Block = (b, head, 8x8 q-tile), 392 blocks.
// ---------------------------------------------------------------------------
#define KSWZ(row, colbytes) (((row) * 64 + (colbytes)) ^ (((row) & 7) << 4))

__global__ __launch_bounds__(256) void natten_mfma(const uint16_t* __restrict__ qkv,
                                                   const float* __restrict__ rpb,
                                                   uint16_t* __restrict__ out) {
  __shared__ uint16_t s_k[224 * 32];
  __shared__ uint16_t s_vt[32][232];
  __shared__ uint16_t s_p[64][232];
  __shared__ float s_rpb[169];

  int tid = threadIdx.x;
  int blk = blockIdx.x;
  int bh = blk & 7, tile = blk >> 3;
  int b = bh >> 2, head = bh & 3;
  int ti = tile / 7, tj = tile % 7;
  int i0 = ti * 8, j0 = tj * 8;
  int rbase = min(max(i0 - 3, 0), 42);
  int cbase = min(max(j0 - 3, 0), 42);

  const bf16x8 bz = {0, 0, 0, 0, 0, 0, 0, 0};
  const f32x4 fz = {0.f, 0.f, 0.f, 0.f};

  if (tid < 112)
    *(bf16x8*)((char*)s_k + KSWZ(196 + (tid >> 2), (tid & 3) * 16)) = bz;
  for (int idx = tid; idx < 1024; idx += 256) s_vt[idx >> 5][196 + (idx & 31)] = 0;
  for (int idx = tid; idx < 784; idx += 256) {
    int pos = idx >> 2, ch = (idx & 3) * 8;
    int r = rbase + pos / 14, c = cbase + pos % 14;
    const uint16_t* base = qkv + ((size_t)(b * 3136 + r * 56 + c)) * 384 + head * 32 + ch;
    bf16x8 kv = *(const bf16x8*)(base + 128);
    bf16x8 vv = *(const bf16x8*)(base + 256);
    *(bf16x8*)((char*)s_k + KSWZ(pos, ch * 2)) = kv;
#pragma unroll
    for (int e = 0; e < 8; ++e) s_vt[ch + e][pos] = (uint16_t)vv[e];
  }
  for (int idx = tid; idx < 169; idx += 256) s_rpb[idx] = rpb[head * 169 + idx];
  __syncthreads();

  int lane = tid & 63, wq = tid >> 6;
  int lc = lane & 15, g = lane >> 4;
  int q0 = wq * 16;

  int pA = q0 + lc;
  int piA = i0 + (pA >> 3), pjA = j0 + (pA & 7);
  bf16x8 qfrag =
      *(const bf16x8*)(qkv + ((size_t)(b * 3136 + piA * 56 + pjA)) * 384 + head * 32 + g * 8);

  f32x4 S[14];
#pragma unroll
  for (int t = 0; t < 14; ++t) {
    bf16x8 kfrag = *(const bf16x8*)((char*)s_k + KSWZ(t * 16 + lc, g * 16));
    S[t] = __builtin_amdgcn_mfma_f32_16x16x32_bf16(qfrag, kfrag, fz, 0, 0, 0);
  }

  int qi = wq * 2 + (g >> 1);
  int i = i0 + qi;
  int a = min(max(i - 3, 0), 49) - rbase;
  int brc = 6 - (i0 - rbase) - qi;
  int bj[4], bcc[4];
#pragma unroll
  for (int jj = 0; jj < 4; ++jj) {
    int qj = 4 * (g & 1) + jj;
    int j = j0 + qj;
    bj[jj] = min(max(j - 3, 0), 49) - cbase;
    bcc[jj] = 6 - (j0 - cbase) - qj;
  }

  float mx[4] = {-1e30f, -1e30f, -1e30f, -1e30f};
  int kr = (lc >= 14) ? 1 : 0;
  int kc = lc - 14 * kr;
#pragma unroll
  for (int t = 0; t < 14; ++t) {
    bool vr = (kr >= a) && (kr <= a + 6);
    int brrow = (kr + brc) * 13;
#pragma unroll
    for (int jj = 0; jj < 4; ++jj) {
      float sv = S[t][jj] * 0.17677669529663687f;
      bool v = vr && (kc >= bj[jj]) && (kc <= bj[jj] + 6);
      int bidx = v ? (brrow + kc + bcc[jj]) : 0;
      float val = v ? (sv + s_rpb[bidx]) : -1e30f;
      S[t][jj] = val;
      mx[jj] = fmaxf(mx[jj], val);
    }
    kr += 1;
    kc += 2;
    if (kc >= 14) { kc -= 14; kr += 1; }
  }
#pragma unroll
  for (int jj = 0; jj < 4; ++jj) {
#pragma unroll
    for (int off = 1; off < 16; off <<= 1) mx[jj] = fmaxf(mx[jj], __shfl_xor(mx[jj], off, 64));
  }

  float sm[4] = {0.f, 0.f, 0.f, 0.f};
#pragma unroll
  for (int t = 0; t < 14; ++t) {
#pragma unroll
    for (int jj = 0; jj < 4; ++jj) {
      float e = __expf(S[t][jj] - mx[jj]);
      sm[jj] += e;
      s_p[q0 + g * 4 + jj][t * 16 + lc] = f2bf(e);
    }
  }
#pragma unroll
  for (int jj = 0; jj < 4; ++jj) {
#pragma unroll
    for (int off = 1; off < 16; off <<= 1) sm[jj] += __shfl_xor(sm[jj], off, 64);
    sm[jj] = 1.f / sm[jj];
  }

  __syncthreads();

  f32x4 O[2] = {fz, fz};
#pragma unroll
  for (int k7 = 0; k7 < 7; ++k7) {
    bf16x8 pa = *(const bf16x8*)&s_p[q0 + lc][k7 * 32 + g * 8];
#pragma unroll
    for (int dt = 0; dt < 2; ++dt) {
      bf16x8 vb = *(const bf16x8*)&s_vt[dt * 16 + lc][k7 * 32 + g * 8];
      O[dt] = __builtin_amdgcn_mfma_f32_16x16x32_bf16(pa, vb, O[dt], 0, 0, 0);
    }
  }

#pragma unroll
  for (int jj = 0; jj < 4; ++jj) {
    int q = q0 + g * 4 + jj;
    int pi = i0 + (q >> 3), pj = j0 + (q & 7);
    size_t ob = ((size_t)(b * 3136 + pi * 56 + pj)) * 128 + head * 32;
    out[ob + lc] = f2bf(O[0][jj] * sm[jj]);
    out[ob + 16 + lc] = f2bf(O[1][jj] * sm[jj]);
  }
}

// ---------------------------------------------------------------------------
// Implicit-im2col conv GEMM: 3x3 s2 p1, 128->256. M=1568, K=1152, N=256.
// Grid (25,4), 64x64 tiles. LDS-routed coalesced epilogue.
// ---------------------------------------------------------------------------
__global__ __launch_bounds__(256) void conv_gemm(const float* __restrict__ x,
                                                 const uint16_t* __restrict__ Wt,
                                                 float* __restrict__ out) {
  __shared__ __align__(16) char csm[18432];  // sA[64][72] | sB[64][72]
  uint16_t(*sA)[72] = (uint16_t(*)[72])csm;
  uint16_t(*sB)[72] = (uint16_t(*)[72])(csm + 9216);
  float(*sC)[68] = (float(*)[68])csm;  // 17408 B alias

  int m0 = blockIdx.x * 64, n0 = blockIdx.y * 64;
  int tid = threadIdx.x, lane = tid & 63, wid = tid >> 6;
  int wr = (wid >> 1) * 32, wc = (wid & 1) * 32;
  int lrow = lane & 15, lko = (lane >> 4) * 8;

  f32x4 acc00 = {0.f, 0.f, 0.f, 0.f}, acc01 = acc00, acc10 = acc00, acc11 = acc00;

  int r = tid >> 2, c0 = (tid & 3) * 16;
  int opix = m0 + r;
  bool rowok = opix < 1568;
  int ow = opix % 28, oh = (opix / 28) % 28, bb = opix / 784;

#pragma unroll
  for (int ks = 0; ks < 18; ++ks) {
    int kk = ks >> 1, ic0 = (ks & 1) * 64;
    int kh = kk / 3, kw = kk - kh * 3;
    int ih = 2 * oh - 1 + kh, iw = 2 * ow - 1 + kw;
    float4 v0 = {0.f, 0.f, 0.f, 0.f}, v1 = v0, v2 = v0, v3 = v0;
    if (rowok && ih >= 0 && ih < 56 && iw >= 0 && iw < 56) {
      const float4* p = (const float4*)(x + (size_t)((bb * 56 + ih) * 56 + iw) * 128 + ic0 + c0);
      v0 = p[0]; v1 = p[1]; v2 = p[2]; v3 = p[3];
    }
    union { uint16_t us[8]; bf16x8 v; } ta, tb;
    ta.us[0] = f2bf(v0.x); ta.us[1] = f2bf(v0.y); ta.us[2] = f2bf(v0.z); ta.us[3] = f2bf(v0.w);
    ta.us[4] = f2bf(v1.x); ta.us[5] = f2bf(v1.y); ta.us[6] = f2bf(v1.z); ta.us[7] = f2bf(v1.w);
    tb.us[0] = f2bf(v2.x); tb.us[1] = f2bf(v2.y); tb.us[2] = f2bf(v2.z); tb.us[3] = f2bf(v2.w);
    tb.us[4] = f2bf(v3.x); tb.us[5] = f2bf(v3.y); tb.us[6] = f2bf(v3.z); tb.us[7] = f2bf(v3.w);
    *(bf16x8*)&sA[r][c0] = ta.v;
    *(bf16x8*)&sA[r][c0 + 8] = tb.v;
#pragma unroll
    for (int it = 0; it < 2; ++it) {
      int chunk = tid + it * 256;
      int row = chunk >> 3, kc = (chunk & 7) * 8;
      *(bf16x8*)&sB[row][kc] = *(const bf16x8*)(Wt + (size_t)(n0 + row) * 1152 + ks * 64 + kc);
    }
    __syncthreads();
#pragma unroll
    for (int kk2 = 0; kk2 < 64; kk2 += 32) {
      bf16x8 a0 = *(const bf16x8*)&sA[wr + lrow][kk2 + lko];
      bf16x8 a1 = *(const bf16x8*)&sA[wr + 16 + lrow][kk2 + lko];
      bf16x8 b0 = *(const bf16x8*)&sB[wc + lrow][kk2 + lko];
      bf16x8 b1 = *(const bf16x8*)&sB[wc + 16 + lrow][kk2 + lko];
      acc00 = __builtin_amdgcn_mfma_f32_16x16x32_bf16(a0, b0, acc00, 0, 0, 0);
      acc01 = __builtin_amdgcn_mfma_f32_16x16x32_bf16(a0, b1, acc01, 0, 0, 0);
      acc10 = __builtin_amdgcn_mfma_f32_16x16x32_bf16(a1, b0, acc10, 0, 0, 0);
      acc11 = __builtin_amdgcn_mfma_f32_16x16x32_bf16(a1, b1, acc11, 0, 0, 0);
    }
    __syncthreads();
  }

  // epilogue via LDS
  {
    int lc = lane & 15, g = lane >> 4;
    f32x4 av[2][2] = {{acc00, acc01}, {acc10, acc11}};
#pragma unroll
    for (int mi = 0; mi < 2; ++mi)
#pragma unroll
      for (int ni = 0; ni < 2; ++ni)
#pragma unroll
        for (int j = 0; j < 4; ++j)
          sC[wr + mi * 16 + g * 4 + j][wc + ni * 16 + lc] = av[mi][ni][j];
    __syncthreads();
    int rr = tid >> 2, cs = (tid & 3) * 16;
    int grow = m0 + rr;
    if (grow < 1568) {
      const float4* cp = (const float4*)&sC[rr][cs];
      float4* op = (float4*)(out + (size_t)grow * 256 + n0 + cs);
#pragma unroll
      for (int u = 0; u < 4; ++u) op[u] = cp[u];
    }
  }
}

extern "C" void kernel_launch(void* const* d_in, const int* in_sizes, int n_in,
                              void* d_out, int out_size, void* d_ws, size_t ws_size,
                              hipStream_t stream) {
  const float* x    = (const float*)d_in[0];
  const float* n1w  = (const float*)d_in[1];
  const float* n1b  = (const float*)d_in[2];
  const float* qkvw = (const float*)d_in[3];
  const float* qkvb = (const float*)d_in[4];
  const float* rpb  = (const float*)d_in[5];
  const float* pw   = (const float*)d_in[6];
  const float* pb   = (const float*)d_in[7];
  const float* n2w  = (const float*)d_in[8];
  const float* n2b  = (const float*)d_in[9];
  const float* f1w  = (const float*)d_in[10];
  const float* f1b  = (const float*)d_in[11];
  const float* f2w  = (const float*)d_in[12];
  const float* f2b  = (const float*)d_in[13];
  const float* cw   = (const float*)d_in[14];
  const float* dnw  = (const float*)d_in[15];
  const float* dnb  = (const float*)d_in[16];
  float* out = (float*)d_out;

  char* wsb = (char*)d_ws;
  float*    xbuf    = (float*)(wsb + 0);          // 3211264 B
  uint16_t* qkv_b   = (uint16_t*)(wsb + 3211264); // 4816896 B
  uint16_t* att_b   = (uint16_t*)(wsb + 8028160); // 1605632 B
  uint16_t* hid_b   = (uint16_t*)(wsb + 9633792); // 6422528 B
  float*    convout = (float*)(wsb + 16056320);   // 1605632 B
  uint16_t* wts     = (uint16_t*)(wsb + 17661952);// 1376256 B
  uint16_t* qkvwt = wts;            // 2 x 384x128
  uint16_t* pwt   = wts + 98304;    // 2 x 128x128
  uint16_t* f1wt  = wts + 131072;   // 2 x 512x128
  uint16_t* f2wt  = wts + 262144;   // 2 x 128x512
  uint16_t* cwt   = wts + 393216;   // 256x1152

  PrepArgs pa;
  pa.src[0] = qkvw;         pa.dst[0] = qkvwt;          pa.K[0] = 128; pa.N[0] = 384;
  pa.src[1] = qkvw + 49152; pa.dst[1] = qkvwt + 49152;  pa.K[1] = 128; pa.N[1] = 384;
  pa.src[2] = pw;           pa.dst[2] = pwt;            pa.K[2] = 128; pa.N[2] = 128;
  pa.src[3] = pw + 16384;   pa.dst[3] = pwt + 16384;    pa.K[3] = 128; pa.N[3] = 128;
  pa.src[4] = f1w;          pa.dst[4] = f1wt;           pa.K[4] = 128; pa.N[4] = 512;
  pa.src[5] = f1w + 65536;  pa.dst[5] = f1wt + 65536;   pa.K[5] = 128; pa.N[5] = 512;
  pa.src[6] = f2w;          pa.dst[6] = f2wt;           pa.K[6] = 512; pa.N[6] = 128;
  pa.src[7] = f2w + 65536;  pa.dst[7] = f2wt + 65536;   pa.K[7] = 512; pa.N[7] = 128;
  pa.src[8] = cw;           pa.dst[8] = cwt;            pa.K[8] = 1152; pa.N[8] = 256;
  int cums[10] = {0, 48, 96, 112, 128, 192, 256, 320, 384, 672};
  for (int u = 0; u < 10; ++u) pa.cum[u] = cums[u];
  prep_weights<<<672, 256, 0, stream>>>(pa);

  for (int i = 0; i < 2; ++i) {
    const float* xin = (i == 0) ? x : xbuf;
    // qkv GEMM with LN1 fused into A-staging
    mfma_gemm<128, 384, 0, 0, 1, 1><<<dim3(98, 6), 256, 0, stream>>>(
        nullptr, xin, n1w + i * 128, n1b + i * 128, qkvwt + i * 49152, qkvb + i * 384,
        nullptr, nullptr, qkv_b, nullptr, 6272);
    natten_mfma<<<392, 256, 0, stream>>>(qkv_b, rpb + i * 676, att_b);
    // proj + residual
    mfma_gemm<128, 128, 0, 1, 0, 0><<<dim3(98, 2), 256, 0, stream>>>(
        att_b, nullptr, nullptr, nullptr, pwt + i * 16384, pb + i * 128,
        xin, xbuf, nullptr, nullptr, 6272);
    // fc1 with LN2 fused, GELU
    mfma_gemm<128, 512, 1, 0, 1, 1><<<dim3(98, 8), 256, 0, stream>>>(
        nullptr, xbuf, n2w + i * 128, n2b + i * 128, f1wt + i * 65536, f1b + i * 512,
        nullptr, nullptr, hid_b, nullptr, 6272);
    // fc2 + residual (layer 1 also writes the x-output copy)
    mfma_gemm<512, 128, 0, 1, 0, 0><<<dim3(98, 2), 256, 0, stream>>>(
        hid_b, nullptr, nullptr, nullptr, f2wt + i * 65536, f2b + i * 128,
        xbuf, xbuf, nullptr, (i == 1) ? (out + 401408) : nullptr, 6272);
  }

  conv_gemm<<<dim3(25, 4), 256, 0, stream>>>(xbuf, cwt, convout);
  ln256_kernel<<<392, 256, 0, stream>>>(convout, out, dnw, dnb);
}

// Round 7
// 101.571 us; speedup vs baseline: 3.8099x; 1.4946x over previous
//
#include <hip/hip_runtime.h>
#include <stdint.h>

// ---------------------------------------------------------------------------
// NAT block forward: B=2, H=W=56, C=128, nh=4, hd=32, K=7, depth=2, hidden=512
// Round 7: occupancy pass. 32x64 GEMM tiles (6 blk/CU), conv split-K by kh.
// ---------------------------------------------------------------------------

typedef __attribute__((ext_vector_type(8))) short bf16x8;
typedef __attribute__((ext_vector_type(4))) float f32x4;

__device__ __forceinline__ float bf2f(uint16_t u) {
  union { uint32_t u; float f; } t;
  t.u = (uint32_t)u << 16;
  return t.f;
}
__device__ __forceinline__ uint16_t f2bf(float f) {
  union { float f; uint32_t u; } t;
  t.f = f;
  return (uint16_t)((t.u + 0x7FFFu + ((t.u >> 16) & 1u)) >> 16);
}

// ---------------------------------------------------------------------------
// One-shot weight prep: 9 transpose+bf16 jobs in one launch (672 blocks).
// ---------------------------------------------------------------------------
struct PrepArgs {
  const float* src[9];
  uint16_t* dst[9];
  int K[9], N[9];
  int cum[10];
};

__global__ __launch_bounds__(256) void prep_weights(PrepArgs a) {
  __shared__ float t[32][33];
  int bt = blockIdx.x;
  int j = 0;
#pragma unroll
  for (int u = 0; u < 9; ++u)
    if (bt >= a.cum[u + 1]) j = u + 1;
  int lt = bt - a.cum[j];
  const float* w = a.src[j];
  uint16_t* wt = a.dst[j];
  int K = a.K[j], N = a.N[j];
  int tn = N >> 5;
  int n0 = (lt % tn) * 32, k0 = (lt / tn) * 32;
  int tx = threadIdx.x & 31, ty = threadIdx.x >> 5;
#pragma unroll
  for (int r2 = 0; r2 < 32; r2 += 8)
    t[ty + r2][tx] = w[(size_t)(k0 + ty + r2) * N + n0 + tx];
  __syncthreads();
#pragma unroll
  for (int r2 = 0; r2 < 32; r2 += 8)
    wt[(size_t)(n0 + ty + r2) * K + k0 + tx] = f2bf(t[tx][ty + r2]);
}

// LayerNorm over C=256 of (p0+p1+p2), fp32 -> fp32 out. Wave per pixel.
__global__ __launch_bounds__(256) void ln256_kernel(const float* __restrict__ p0,
                                                    const float* __restrict__ p1,
                                                    const float* __restrict__ p2,
                                                    float* __restrict__ out,
                                                    const float* __restrict__ w,
                                                    const float* __restrict__ b) {
  int wave = threadIdx.x >> 6, lane = threadIdx.x & 63;
  int pix = blockIdx.x * 4 + wave;
  size_t base = (size_t)pix * 256;
  float v0 = p0[base + lane] + p1[base + lane] + p2[base + lane];
  float v1 = p0[base + lane + 64] + p1[base + lane + 64] + p2[base + lane + 64];
  float v2 = p0[base + lane + 128] + p1[base + lane + 128] + p2[base + lane + 128];
  float v3 = p0[base + lane + 192] + p1[base + lane + 192] + p2[base + lane + 192];
  float s = v0 + v1 + v2 + v3;
  float s2 = v0 * v0 + v1 * v1 + v2 * v2 + v3 * v3;
#pragma unroll
  for (int off = 32; off; off >>= 1) {
    s += __shfl_xor(s, off, 64);
    s2 += __shfl_xor(s2, off, 64);
  }
  float mu = s * (1.f / 256.f);
  float var = s2 * (1.f / 256.f) - mu * mu;
  float r = rsqrtf(var + 1e-5f);
  float* q = out + base;
  q[lane] = (v0 - mu) * r * w[lane] + b[lane];
  q[lane + 64] = (v1 - mu) * r * w[lane + 64] + b[lane + 64];
  q[lane + 128] = (v2 - mu) * r * w[lane + 128] + b[lane + 128];
  q[lane + 192] = (v3 - mu) * r * w[lane + 192] + b[lane + 192];
}

// ---------------------------------------------------------------------------
// MFMA GEMM, 32x64 tile, 4 waves (2x2), wave = 16x32. 8 MFMA/wave per K=128.
// ---------------------------------------------------------------------------
template <int KD, int ND, int ACT, int RES, int OUTB, int LNF>
__global__ __launch_bounds__(256) void mfma_gemm32(
    const uint16_t* __restrict__ A, const float* __restrict__ Af,
    const float* __restrict__ lnw, const float* __restrict__ lnb,
    const uint16_t* __restrict__ Wt, const float* __restrict__ bias,
    const float* __restrict__ res, float* __restrict__ outf,
    uint16_t* __restrict__ outb, float* __restrict__ outf2, int M) {
  __shared__ __align__(16) char smem[26112];  // sA[32][136] | sB[64][136]
  uint16_t(*sA)[136] = (uint16_t(*)[136])smem;
  uint16_t(*sB)[136] = (uint16_t(*)[136])(smem + 8704);
  float(*sC)[68] = (float(*)[68])smem;  // epilogue alias (8704 B)

  int m0 = blockIdx.x * 32, n0 = blockIdx.y * 64;
  int tid = threadIdx.x, lane = tid & 63, wid = tid >> 6;
  int wr = (wid >> 1) * 16, wc = (wid & 1) * 32;
  int lc = lane & 15, g = lane >> 4;
  int lko = g * 8;

  f32x4 acc0 = {0.f, 0.f, 0.f, 0.f}, acc1 = acc0;

  constexpr int NCH = KD / 128;
#pragma unroll
  for (int c = 0; c < NCH; ++c) {
    if constexpr (LNF) {
      int r = tid >> 3, qt = tid & 7;
      const float4* xr = (const float4*)(Af + (size_t)(m0 + r) * 128 + qt * 16);
      float4 xv[4];
      float s = 0.f, s2 = 0.f;
#pragma unroll
      for (int u = 0; u < 4; ++u) {
        xv[u] = xr[u];
        s += xv[u].x + xv[u].y + xv[u].z + xv[u].w;
        s2 += xv[u].x * xv[u].x + xv[u].y * xv[u].y + xv[u].z * xv[u].z + xv[u].w * xv[u].w;
      }
      s += __shfl_xor(s, 1, 64);
      s += __shfl_xor(s, 2, 64);
      s += __shfl_xor(s, 4, 64);
      s2 += __shfl_xor(s2, 1, 64);
      s2 += __shfl_xor(s2, 2, 64);
      s2 += __shfl_xor(s2, 4, 64);
      float mu = s * (1.f / 128.f);
      float var = s2 * (1.f / 128.f) - mu * mu;
      float rstd = rsqrtf(var + 1e-5f);
      const float* lw = lnw + qt * 16;
      const float* lb = lnb + qt * 16;
      union { uint16_t us[8]; bf16x8 v; } tq[2];
#pragma unroll
      for (int u = 0; u < 4; ++u) {
        tq[u >> 1].us[(u & 1) * 4 + 0] = f2bf((xv[u].x - mu) * rstd * lw[u * 4 + 0] + lb[u * 4 + 0]);
        tq[u >> 1].us[(u & 1) * 4 + 1] = f2bf((xv[u].y - mu) * rstd * lw[u * 4 + 1] + lb[u * 4 + 1]);
        tq[u >> 1].us[(u & 1) * 4 + 2] = f2bf((xv[u].z - mu) * rstd * lw[u * 4 + 2] + lb[u * 4 + 2]);
        tq[u >> 1].us[(u & 1) * 4 + 3] = f2bf((xv[u].w - mu) * rstd * lw[u * 4 + 3] + lb[u * 4 + 3]);
      }
      *(bf16x8*)&sA[r][qt * 16] = tq[0].v;
      *(bf16x8*)&sA[r][qt * 16 + 8] = tq[1].v;
    } else {
#pragma unroll
      for (int it = 0; it < 2; ++it) {
        int chunk = tid + it * 256;
        int row = chunk >> 4, kc = (chunk & 15) * 8;
        *(bf16x8*)&sA[row][kc] =
            *(const bf16x8*)(A + (size_t)(m0 + row) * KD + c * 128 + kc);
      }
    }
#pragma unroll
    for (int it = 0; it < 4; ++it) {
      int chunk = tid + it * 256;
      int row = chunk >> 4, kc = (chunk & 15) * 8;
      *(bf16x8*)&sB[row][kc] =
          *(const bf16x8*)(Wt + (size_t)(n0 + row) * KD + c * 128 + kc);
    }
    __syncthreads();
#pragma unroll
    for (int kk = 0; kk < 128; kk += 32) {
      bf16x8 a0 = *(const bf16x8*)&sA[wr + lc][kk + lko];
      bf16x8 b0 = *(const bf16x8*)&sB[wc + lc][kk + lko];
      bf16x8 b1 = *(const bf16x8*)&sB[wc + 16 + lc][kk + lko];
      acc0 = __builtin_amdgcn_mfma_f32_16x16x32_bf16(a0, b0, acc0, 0, 0, 0);
      acc1 = __builtin_amdgcn_mfma_f32_16x16x32_bf16(a0, b1, acc1, 0, 0, 0);
    }
    __syncthreads();
  }

  {
    float bv0 = bias ? bias[n0 + wc + lc] : 0.f;
    float bv1 = bias ? bias[n0 + wc + lc + 16] : 0.f;
#pragma unroll
    for (int ni = 0; ni < 2; ++ni) {
      float bv = ni ? bv1 : bv0;
      f32x4 av = ni ? acc1 : acc0;
#pragma unroll
      for (int j = 0; j < 4; ++j) {
        float a = av[j] + bv;
        if (ACT) a = 0.5f * a * (1.f + erff(a * 0.70710678118654752f));
        sC[wr + g * 4 + j][wc + ni * 16 + lc] = a;
      }
    }
    __syncthreads();
    int r = tid >> 3, cs = (tid & 7) * 8;
    int grow = m0 + r;
    if (grow < M) {
      const float4* cp = (const float4*)&sC[r][cs];
      float4 c4[2] = {cp[0], cp[1]};
      if (RES) {
        const float4* rp = (const float4*)(res + (size_t)grow * ND + n0 + cs);
#pragma unroll
        for (int u = 0; u < 2; ++u) {
          float4 rv = rp[u];
          c4[u].x += rv.x; c4[u].y += rv.y; c4[u].z += rv.z; c4[u].w += rv.w;
        }
      }
      if (OUTB) {
        union { uint16_t us[8]; bf16x8 v; } t;
#pragma unroll
        for (int u = 0; u < 2; ++u) {
          t.us[u * 4 + 0] = f2bf(c4[u].x);
          t.us[u * 4 + 1] = f2bf(c4[u].y);
          t.us[u * 4 + 2] = f2bf(c4[u].z);
          t.us[u * 4 + 3] = f2bf(c4[u].w);
        }
        *(bf16x8*)(outb + (size_t)grow * ND + n0 + cs) = t.v;
      } else {
        float4* op = (float4*)(outf + (size_t)grow * ND + n0 + cs);
        op[0] = c4[0];
        op[1] = c4[1];
        if (outf2) {
          float4* op2 = (float4*)(outf2 + (size_t)grow * ND + n0 + cs);
          op2[0] = c4[0];
          op2[1] = c4[1];
        }
      }
    }
  }
}

// ---------------------------------------------------------------------------
// Neighborhood attention via MFMA. Block = (b, head, 8x8 q-tile), 392 blocks.
// ---------------------------------------------------------------------------
#define KSWZ(row, colbytes) (((row) * 64 + (colbytes)) ^ (((row) & 7) << 4))

__global__ __launch_bounds__(256) void natten_mfma(const uint16_t* __restrict__ qkv,
                                                   const float* __restrict__ rpb,
                                                   uint16_t* __restrict__ out) {
  __shared__ uint16_t s_k[224 * 32];
  __shared__ uint16_t s_vt[32][232];
  __shared__ uint16_t s_p[64][232];
  __shared__ float s_rpb[169];

  int tid = threadIdx.x;
  int blk = blockIdx.x;
  int bh = blk & 7, tile = blk >> 3;
  int b = bh >> 2, head = bh & 3;
  int ti = tile / 7, tj = tile % 7;
  int i0 = ti * 8, j0 = tj * 8;
  int rbase = min(max(i0 - 3, 0), 42);
  int cbase = min(max(j0 - 3, 0), 42);

  const bf16x8 bz = {0, 0, 0, 0, 0, 0, 0, 0};
  const f32x4 fz = {0.f, 0.f, 0.f, 0.f};

  if (tid < 112)
    *(bf16x8*)((char*)s_k + KSWZ(196 + (tid >> 2), (tid & 3) * 16)) = bz;
  for (int idx = tid; idx < 1024; idx += 256) s_vt[idx >> 5][196 + (idx & 31)] = 0;
  for (int idx = tid; idx < 784; idx += 256) {
    int pos = idx >> 2, ch = (idx & 3) * 8;
    int r = rbase + pos / 14, c = cbase + pos % 14;
    const uint16_t* base = qkv + ((size_t)(b * 3136 + r * 56 + c)) * 384 + head * 32 + ch;
    bf16x8 kv = *(const bf16x8*)(base + 128);
    bf16x8 vv = *(const bf16x8*)(base + 256);
    *(bf16x8*)((char*)s_k + KSWZ(pos, ch * 2)) = kv;
#pragma unroll
    for (int e = 0; e < 8; ++e) s_vt[ch + e][pos] = (uint16_t)vv[e];
  }
  for (int idx = tid; idx < 169; idx += 256) s_rpb[idx] = rpb[head * 169 + idx];
  __syncthreads();

  int lane = tid & 63, wq = tid >> 6;
  int lc = lane & 15, g = lane >> 4;
  int q0 = wq * 16;

  int pA = q0 + lc;
  int piA = i0 + (pA >> 3), pjA = j0 + (pA & 7);
  bf16x8 qfrag =
      *(const bf16x8*)(qkv + ((size_t)(b * 3136 + piA * 56 + pjA)) * 384 + head * 32 + g * 8);

  f32x4 S[14];
#pragma unroll
  for (int t = 0; t < 14; ++t) {
    bf16x8 kfrag = *(const bf16x8*)((char*)s_k + KSWZ(t * 16 + lc, g * 16));
    S[t] = __builtin_amdgcn_mfma_f32_16x16x32_bf16(qfrag, kfrag, fz, 0, 0, 0);
  }

  int qi = wq * 2 + (g >> 1);
  int i = i0 + qi;
  int a = min(max(i - 3, 0), 49) - rbase;
  int brc = 6 - (i0 - rbase) - qi;
  int bj[4], bcc[4];
#pragma unroll
  for (int jj = 0; jj < 4; ++jj) {
    int qj = 4 * (g & 1) + jj;
    int j = j0 + qj;
    bj[jj] = min(max(j - 3, 0), 49) - cbase;
    bcc[jj] = 6 - (j0 - cbase) - qj;
  }

  float mx[4] = {-1e30f, -1e30f, -1e30f, -1e30f};
  int kr = (lc >= 14) ? 1 : 0;
  int kc = lc - 14 * kr;
#pragma unroll
  for (int t = 0; t < 14; ++t) {
    bool vr = (kr >= a) && (kr <= a + 6);
    int brrow = (kr + brc) * 13;
#pragma unroll
    for (int jj = 0; jj < 4; ++jj) {
      float sv = S[t][jj] * 0.17677669529663687f;
      bool v = vr && (kc >= bj[jj]) && (kc <= bj[jj] + 6);
      int bidx = v ? (brrow + kc + bcc[jj]) : 0;
      float val = v ? (sv + s_rpb[bidx]) : -1e30f;
      S[t][jj] = val;
      mx[jj] = fmaxf(mx[jj], val);
    }
    kr += 1;
    kc += 2;
    if (kc >= 14) { kc -= 14; kr += 1; }
  }
#pragma unroll
  for (int jj = 0; jj < 4; ++jj) {
#pragma unroll
    for (int off = 1; off < 16; off <<= 1) mx[jj] = fmaxf(mx[jj], __shfl_xor(mx[jj], off, 64));
  }

  float sm[4] = {0.f, 0.f, 0.f, 0.f};
#pragma unroll
  for (int t = 0; t < 14; ++t) {
#pragma unroll
    for (int jj = 0; jj < 4; ++jj) {
      float e = __expf(S[t][jj] - mx[jj]);
      sm[jj] += e;
      s_p[q0 + g * 4 + jj][t * 16 + lc] = f2bf(e);
    }
  }
#pragma unroll
  for (int jj = 0; jj < 4; ++jj) {
#pragma unroll
    for (int off = 1; off < 16; off <<= 1) sm[jj] += __shfl_xor(sm[jj], off, 64);
    sm[jj] = 1.f / sm[jj];
  }

  __syncthreads();

  f32x4 O[2] = {fz, fz};
#pragma unroll
  for (int k7 = 0; k7 < 7; ++k7) {
    bf16x8 pa = *(const bf16x8*)&s_p[q0 + lc][k7 * 32 + g * 8];
#pragma unroll
    for (int dt = 0; dt < 2; ++dt) {
      bf16x8 vb = *(const bf16x8*)&s_vt[dt * 16 + lc][k7 * 32 + g * 8];
      O[dt] = __builtin_amdgcn_mfma_f32_16x16x32_bf16(pa, vb, O[dt], 0, 0, 0);
    }
  }

#pragma unroll
  for (int jj = 0; jj < 4; ++jj) {
    int q = q0 + g * 4 + jj;
    int pi = i0 + (q >> 3), pj = j0 + (q & 7);
    size_t ob = ((size_t)(b * 3136 + pi * 56 + pj)) * 128 + head * 32;
    out[ob + lc] = f2bf(O[0][jj] * sm[jj]);
    out[ob + 16 + lc] = f2bf(O[1][jj] * sm[jj]);
  }
}

// ---------------------------------------------------------------------------
// Conv GEMM, split-K by kh (blockIdx.z). Grid (49, 4, 3). 32x64 tile.
// Writes f32 partial (no bias) to part[kh].
// ---------------------------------------------------------------------------
__global__ __launch_bounds__(256) void conv_gemm32(const float* __restrict__ x,
                                                   const uint16_t* __restrict__ Wt,
                                                   float* __restrict__ parts) {
  __shared__ __align__(16) char smem[26112];
  uint16_t(*sA)[136] = (uint16_t(*)[136])smem;
  uint16_t(*sB)[136] = (uint16_t(*)[136])(smem + 8704);
  float(*sC)[68] = (float(*)[68])smem;

  int m0 = blockIdx.x * 32, n0 = blockIdx.y * 64, kh = blockIdx.z;
  float* part = parts + (size_t)kh * 1568 * 256;
  int tid = threadIdx.x, lane = tid & 63, wid = tid >> 6;
  int wr = (wid >> 1) * 16, wc = (wid & 1) * 32;
  int lc = lane & 15, g = lane >> 4;
  int lko = g * 8;

  f32x4 acc0 = {0.f, 0.f, 0.f, 0.f}, acc1 = acc0;

  int r = tid >> 3, qt = tid & 7;
  int opix = m0 + r;
  int ow = opix % 28, oh = (opix / 28) % 28, bb = opix / 784;
  int ih = 2 * oh - 1 + kh;
  bool rowok = (ih >= 0) && (ih < 56);

#pragma unroll
  for (int kwc = 0; kwc < 3; ++kwc) {
    int iw = 2 * ow - 1 + kwc;
    float4 xv[4] = {{0.f, 0.f, 0.f, 0.f}, {0.f, 0.f, 0.f, 0.f},
                    {0.f, 0.f, 0.f, 0.f}, {0.f, 0.f, 0.f, 0.f}};
    if (rowok && iw >= 0 && iw < 56) {
      const float4* p =
          (const float4*)(x + (size_t)((bb * 56 + ih) * 56 + iw) * 128 + qt * 16);
#pragma unroll
      for (int u = 0; u < 4; ++u) xv[u] = p[u];
    }
    union { uint16_t us[8]; bf16x8 v; } tq[2];
#pragma unroll
    for (int u = 0; u < 4; ++u) {
      tq[u >> 1].us[(u & 1) * 4 + 0] = f2bf(xv[u].x);
      tq[u >> 1].us[(u & 1) * 4 + 1] = f2bf(xv[u].y);
      tq[u >> 1].us[(u & 1) * 4 + 2] = f2bf(xv[u].z);
      tq[u >> 1].us[(u & 1) * 4 + 3] = f2bf(xv[u].w);
    }
    *(bf16x8*)&sA[r][qt * 16] = tq[0].v;
    *(bf16x8*)&sA[r][qt * 16 + 8] = tq[1].v;
#pragma unroll
    for (int it = 0; it < 4; ++it) {
      int chunk = tid + it * 256;
      int row = chunk >> 4, kc = (chunk & 15) * 8;
      *(bf16x8*)&sB[row][kc] =
          *(const bf16x8*)(Wt + (size_t)(n0 + row) * 1152 + kh * 384 + kwc * 128 + kc);
    }
    __syncthreads();
#pragma unroll
    for (int kk = 0; kk < 128; kk += 32) {
      bf16x8 a0 = *(const bf16x8*)&sA[wr + lc][kk + lko];
      bf16x8 b0 = *(const bf16x8*)&sB[wc + lc][kk + lko];
      bf16x8 b1 = *(const bf16x8*)&sB[wc + 16 + lc][kk + lko];
      acc0 = __builtin_amdgcn_mfma_f32_16x16x32_bf16(a0, b0, acc0, 0, 0, 0);
      acc1 = __builtin_amdgcn_mfma_f32_16x16x32_bf16(a0, b1, acc1, 0, 0, 0);
    }
    __syncthreads();
  }

#pragma unroll
  for (int ni = 0; ni < 2; ++ni) {
    f32x4 av = ni ? acc1 : acc0;
#pragma unroll
    for (int j = 0; j < 4; ++j) sC[wr + g * 4 + j][wc + ni * 16 + lc] = av[j];
  }
  __syncthreads();
  int rr = tid >> 3, cs = (tid & 7) * 8;
  int grow = m0 + rr;
  if (grow < 1568) {
    const float4* cp = (const float4*)&sC[rr][cs];
    float4* op = (float4*)(part + (size_t)grow * 256 + n0 + cs);
    op[0] = cp[0];
    op[1] = cp[1];
  }
}

extern "C" void kernel_launch(void* const* d_in, const int* in_sizes, int n_in,
                              void* d_out, int out_size, void* d_ws, size_t ws_size,
                              hipStream_t stream) {
  const float* x    = (const float*)d_in[0];
  const float* n1w  = (const float*)d_in[1];
  const float* n1b  = (const float*)d_in[2];
  const float* qkvw = (const float*)d_in[3];
  const float* qkvb = (const float*)d_in[4];
  const float* rpb  = (const float*)d_in[5];
  const float* pw   = (const float*)d_in[6];
  const float* pb   = (const float*)d_in[7];
  const float* n2w  = (const float*)d_in[8];
  const float* n2b  = (const float*)d_in[9];
  const float* f1w  = (const float*)d_in[10];
  const float* f1b  = (const float*)d_in[11];
  const float* f2w  = (const float*)d_in[12];
  const float* f2b  = (const float*)d_in[13];
  const float* cw   = (const float*)d_in[14];
  const float* dnw  = (const float*)d_in[15];
  const float* dnb  = (const float*)d_in[16];
  float* out = (float*)d_out;

  char* wsb = (char*)d_ws;
  float*    xbuf    = (float*)(wsb + 0);           // 3211264 B
  uint16_t* qkv_b   = (uint16_t*)(wsb + 3211264);  // 4816896 B (dead by conv)
  uint16_t* att_b   = (uint16_t*)(wsb + 8028160);  // 1605632 B
  uint16_t* hid_b   = (uint16_t*)(wsb + 9633792);  // 6422528 B
  float*    parts   = (float*)(wsb + 16056320);    // 3 x 1605632 B = 4816896 B
  uint16_t* wts     = (uint16_t*)(wsb + 20873216); // 1376256 B -> total 22.2 MB
  uint16_t* qkvwt = wts;            // 2 x 384x128
  uint16_t* pwt   = wts + 98304;    // 2 x 128x128
  uint16_t* f1wt  = wts + 131072;   // 2 x 512x128
  uint16_t* f2wt  = wts + 262144;   // 2 x 128x512
  uint16_t* cwt   = wts + 393216;   // 256x1152

  PrepArgs pa;
  pa.src[0] = qkvw;         pa.dst[0] = qkvwt;          pa.K[0] = 128; pa.N[0] = 384;
  pa.src[1] = qkvw + 49152; pa.dst[1] = qkvwt + 49152;  pa.K[1] = 128; pa.N[1] = 384;
  pa.src[2] = pw;           pa.dst[2] = pwt;            pa.K[2] = 128; pa.N[2] = 128;
  pa.src[3] = pw + 16384;   pa.dst[3] = pwt + 16384;    pa.K[3] = 128; pa.N[3] = 128;
  pa.src[4] = f1w;          pa.dst[4] = f1wt;           pa.K[4] = 128; pa.N[4] = 512;
  pa.src[5] = f1w + 65536;  pa.dst[5] = f1wt + 65536;   pa.K[5] = 128; pa.N[5] = 512;
  pa.src[6] = f2w;          pa.dst[6] = f2wt;           pa.K[6] = 512; pa.N[6] = 128;
  pa.src[7] = f2w + 65536;  pa.dst[7] = f2wt + 65536;   pa.K[7] = 512; pa.N[7] = 128;
  pa.src[8] = cw;           pa.dst[8] = cwt;            pa.K[8] = 1152; pa.N[8] = 256;
  int cums[10] = {0, 48, 96, 112, 128, 192, 256, 320, 384, 672};
  for (int u = 0; u < 10; ++u) pa.cum[u] = cums[u];
  prep_weights<<<672, 256, 0, stream>>>(pa);

  for (int i = 0; i < 2; ++i) {
    const float* xin = (i == 0) ? x : xbuf;
    mfma_gemm32<128, 384, 0, 0, 1, 1><<<dim3(196, 6), 256, 0, stream>>>(
        nullptr, xin, n1w + i * 128, n1b + i * 128, qkvwt + i * 49152, qkvb + i * 384,
        nullptr, nullptr, qkv_b, nullptr, 6272);
    natten_mfma<<<392, 256, 0, stream>>>(qkv_b, rpb + i * 676, att_b);
    mfma_gemm32<128, 128, 0, 1, 0, 0><<<dim3(196, 2), 256, 0, stream>>>(
        att_b, nullptr, nullptr, nullptr, pwt + i * 16384, pb + i * 128,
        xin, xbuf, nullptr, nullptr, 6272);
    mfma_gemm32<128, 512, 1, 0, 1, 1><<<dim3(196, 8), 256, 0, stream>>>(
        nullptr, xbuf, n2w + i * 128, n2b + i * 128, f1wt + i * 65536, f1b + i * 512,
        nullptr, nullptr, hid_b, nullptr, 6272);
    mfma_gemm32<512, 128, 0, 1, 0, 0><<<dim3(196, 2), 256, 0, stream>>>(
        hid_b, nullptr, nullptr, nullptr, f2wt + i * 65536, f2b + i * 128,
        xbuf, xbuf, nullptr, (i == 1) ? (out + 401408) : nullptr, 6272);
  }

  conv_gemm32<<<dim3(49, 4, 3), 256, 0, stream>>>(xbuf, cwt, parts);
  ln256_kernel<<<392, 256, 0, stream>>>(parts, parts + 401408, parts + 802816, out, dnw, dnb);
}